// Round 1
// baseline (6407.481 us; speedup 1.0000x reference)
//
#include <hip/hip_runtime.h>
#include <math.h>

namespace {

constexpr int Bc = 4, Cc = 96, Hc = 56, Wc = 56;
constexpr int HWc = Hc * Wc;       // 3136
constexpr int Nc  = Bc * HWc;      // 12544
constexpr float EPSc = 1e-5f;

__device__ __forceinline__ float gelu_exact(float x) {
  return 0.5f * x * (1.0f + erff(x * 0.7071067811865475f));
}

// ---------------- LayerNorm over channel dim (NCHW) ----------------
__global__ __launch_bounds__(256) void k_ln(const float* __restrict__ x,
                                            const float* __restrict__ g,
                                            const float* __restrict__ b,
                                            float* __restrict__ out) {
  int pos = blockIdx.x * 256 + threadIdx.x;      // 0..N-1
  int bb = pos / HWc, hw = pos % HWc;
  const float* xb = x + (size_t)bb * Cc * HWc + hw;
  float s = 0.f, s2 = 0.f;
  for (int c = 0; c < Cc; ++c) { float v = xb[c * HWc]; s += v; s2 += v * v; }
  float mu  = s * (1.f / Cc);
  float var = fmaxf(s2 * (1.f / Cc) - mu * mu, 0.f);
  float rs  = rsqrtf(var + EPSc);
  float* ob = out + (size_t)bb * Cc * HWc + hw;
  for (int c = 0; c < Cc; ++c) {
    float v = xb[c * HWc];
    ob[c * HWc] = (v - mu) * rs * g[c] + b[c];
  }
}

// ---------------- 1x1 conv 96->96 (block 64x4, wave owns 24 outs) ----------------
__global__ __launch_bounds__(256) void k_pw96(const float* __restrict__ src,
                                              const float* __restrict__ wq,
                                              const float* __restrict__ bq,
                                              float* __restrict__ dst,
                                              float* __restrict__ dstT,
                                              int do_gelu) {
  int spos = blockIdx.x * 64 + threadIdx.x;      // position
  int og = threadIdx.y;                          // 0..3 (wave-uniform)
  int bb = spos / HWc, hw = spos % HWc;
  const float* sb = src + (size_t)bb * Cc * HWc + hw;
  float acc[24];
#pragma unroll
  for (int o = 0; o < 24; ++o) acc[o] = 0.f;
  for (int c = 0; c < Cc; ++c) {
    float v = sb[c * HWc];
    const float* wr = wq + (og * 24) * Cc + c;   // wave-uniform index
#pragma unroll
    for (int o = 0; o < 24; ++o) acc[o] += v * wr[o * Cc];
  }
  float* db_ = dst + (size_t)bb * Cc * HWc + hw;
  float res[24];
#pragma unroll
  for (int o = 0; o < 24; ++o) {
    int oc = og * 24 + o;
    float r = acc[o] + bq[oc];
    if (do_gelu) r = gelu_exact(r);
    res[o] = r;
    db_[oc * HWc] = r;
  }
  if (dstT) {
    float* tb = dstT + ((size_t)bb * HWc + hw) * Cc + og * 24;
#pragma unroll
    for (int o4 = 0; o4 < 6; ++o4) {
      float4 t; t.x = res[o4*4]; t.y = res[o4*4+1]; t.z = res[o4*4+2]; t.w = res[o4*4+3];
      reinterpret_cast<float4*>(tb)[o4] = t;
    }
  }
}

// ---------------- direct KxK conv 96->P (offset convs) ----------------
template <int K, int DIL_, int PAD_, int P>
__global__ __launch_bounds__(256) void k_conv(const float* __restrict__ src,
                                              const float* __restrict__ wq,
                                              const float* __restrict__ bq,
                                              float* __restrict__ dst) {
  constexpr int KK = K * K;
  constexpr int PCH = 13;
  int spos = blockIdx.x * 64 + threadIdx.x;
  int g = blockIdx.y * 4 + threadIdx.y;          // wave-uniform group
  int pbase = g * PCH;
  int bb = spos / HWc, hw = spos % HWc;
  int h = hw / Wc, w = hw % Wc;
  const float* sb = src + (size_t)bb * Cc * HWc;
  float acc[PCH];
#pragma unroll
  for (int j = 0; j < PCH; ++j) acc[j] = 0.f;
  for (int c = 0; c < Cc; ++c) {
    const float* sc = sb + c * HWc;
    for (int ky = 0; ky < K; ++ky) {
      int y = h + ky * DIL_ - PAD_;
      bool yv = (unsigned)y < (unsigned)Hc;
#pragma unroll
      for (int kx = 0; kx < K; ++kx) {
        int x = w + kx * DIL_ - PAD_;
        float v = (yv && (unsigned)x < (unsigned)Wc) ? sc[y * Wc + x] : 0.f;
        const float* wr = wq + (size_t)c * KK + ky * K + kx;
#pragma unroll
        for (int j = 0; j < PCH; ++j) {
          int po = pbase + j;
          if (po < P) acc[j] += v * wr[(size_t)po * Cc * KK];
        }
      }
    }
  }
#pragma unroll
  for (int j = 0; j < PCH; ++j) {
    int po = pbase + j;
    if (po < P) dst[((size_t)bb * P + po) * HWc + hw] = acc[j] + bq[po];
  }
}

// ---------------- deformable depthwise sampling ----------------
// srcT: NHWC [B,HW,C]; off: [B,2*KK,HW]; dw: [C,KK]; db: [C]
template <int K, int DIL_, int PAD_>
__global__ __launch_bounds__(256) void k_deform(const float* __restrict__ srcT,
                                                const float* __restrict__ off,
                                                const float* __restrict__ dwq,
                                                const float* __restrict__ dbq,
                                                float* __restrict__ dst,
                                                float* __restrict__ dstT) {
  constexpr int KK = K * K;
  int tid = blockIdx.x * 256 + threadIdx.x;      // N*24 threads
  int cg = tid % 24;
  int pos = tid / 24;
  int c = cg * 4;
  int bb = pos / HWc, hw = pos % HWc;
  int h = hw / Wc, w = hw % Wc;
  const float* sb = srcT + (size_t)bb * HWc * Cc + c;
  const float* ob = off + (size_t)bb * (2 * KK) * HWc + hw;
  float ax = 0.f, ay = 0.f, az = 0.f, aw = 0.f;
  for (int p = 0; p < KK; ++p) {
    float oy = ob[(2 * p + 0) * HWc];
    float ox = ob[(2 * p + 1) * HWc];
    float py = (float)(h + (p / K) * DIL_ - PAD_) + oy;
    float px = (float)(w + (p % K) * DIL_ - PAD_) + ox;
    float y0f = floorf(py), x0f = floorf(px);
    float wy = py - y0f, wx = px - x0f;
    int y0 = (int)y0f, x0 = (int)x0f;
    float sx = 0.f, sy = 0.f, sz = 0.f, sw = 0.f;
#pragma unroll
    for (int dy = 0; dy < 2; ++dy) {
      int yi = y0 + dy;
      if ((unsigned)yi >= (unsigned)Hc) continue;
      float wyv = dy ? wy : 1.f - wy;
#pragma unroll
      for (int dx = 0; dx < 2; ++dx) {
        int xi = x0 + dx;
        if ((unsigned)xi >= (unsigned)Wc) continue;
        float wt = wyv * (dx ? wx : 1.f - wx);
        const float4 v = *reinterpret_cast<const float4*>(sb + (size_t)(yi * Wc + xi) * Cc);
        sx += wt * v.x; sy += wt * v.y; sz += wt * v.z; sw += wt * v.w;
      }
    }
    float d0 = dwq[(c + 0) * KK + p], d1 = dwq[(c + 1) * KK + p];
    float d2 = dwq[(c + 2) * KK + p], d3 = dwq[(c + 3) * KK + p];
    ax += sx * d0; ay += sy * d1; az += sz * d2; aw += sw * d3;
  }
  ax += dbq[c]; ay += dbq[c + 1]; az += dbq[c + 2]; aw += dbq[c + 3];
  if (dst) {
    float* d = dst + (size_t)bb * Cc * HWc + hw;
    d[(c + 0) * HWc] = ax; d[(c + 1) * HWc] = ay;
    d[(c + 2) * HWc] = az; d[(c + 3) * HWc] = aw;
  }
  if (dstT) {
    float4 t; t.x = ax; t.y = ay; t.z = az; t.w = aw;
    *reinterpret_cast<float4*>(dstT + ((size_t)bb * HWc + hw) * Cc + c) = t;
  }
}

// ---------------- gated projection + shortcut + ls1 + residual ----------------
__global__ __launch_bounds__(256) void k_combine(const float* __restrict__ x,
                                                 const float* __restrict__ u,
                                                 const float* __restrict__ a,
                                                 const float* __restrict__ yln,
                                                 const float* __restrict__ wq,
                                                 const float* __restrict__ bq,
                                                 const float* __restrict__ ls1q,
                                                 float* __restrict__ y2,
                                                 float* __restrict__ xo) {
  int spos = blockIdx.x * 64 + threadIdx.x;
  int og = threadIdx.y;
  int bb = spos / HWc, hw = spos % HWc;
  size_t base = (size_t)bb * Cc * HWc + hw;
  float acc[24];
#pragma unroll
  for (int o = 0; o < 24; ++o) acc[o] = 0.f;
  for (int c = 0; c < Cc; ++c) {
    float v = u[base + (size_t)c * HWc] * a[base + (size_t)c * HWc];
    const float* wr = wq + (og * 24) * Cc + c;
#pragma unroll
    for (int o = 0; o < 24; ++o) acc[o] += v * wr[o * Cc];
  }
#pragma unroll
  for (int o = 0; o < 24; ++o) {
    int oc = og * 24 + o;
    float t = acc[o] + bq[oc] + yln[base + (size_t)oc * HWc];
    float yv = ls1q[oc] * t;
    y2[base + (size_t)oc * HWc] = yv;
    xo[base + (size_t)oc * HWc] = x[base + (size_t)oc * HWc] + yv;
  }
}

// ---------------- MLP: LN2 + f1 (96->4) ----------------
__global__ __launch_bounds__(256) void k_mlp1(const float* __restrict__ y2,
                                              const float* __restrict__ g,
                                              const float* __restrict__ b,
                                              const float* __restrict__ f1wq,
                                              const float* __restrict__ f1bq,
                                              float* __restrict__ z4) {
  int pos = blockIdx.x * 256 + threadIdx.x;
  int bb = pos / HWc, hw = pos % HWc;
  const float* yb = y2 + (size_t)bb * Cc * HWc + hw;
  float s = 0.f, s2 = 0.f;
  for (int c = 0; c < Cc; ++c) { float v = yb[c * HWc]; s += v; s2 += v * v; }
  float mu  = s * (1.f / Cc);
  float var = fmaxf(s2 * (1.f / Cc) - mu * mu, 0.f);
  float rs  = rsqrtf(var + EPSc);
  float a0 = 0.f, a1 = 0.f, a2 = 0.f, a3 = 0.f;
  for (int c = 0; c < Cc; ++c) {
    float t = (yb[c * HWc] - mu) * rs * g[c] + b[c];
    a0 += t * f1wq[0 * Cc + c];
    a1 += t * f1wq[1 * Cc + c];
    a2 += t * f1wq[2 * Cc + c];
    a3 += t * f1wq[3 * Cc + c];
  }
  float* zb = z4 + (size_t)bb * 4 * HWc + hw;
  zb[0 * HWc] = a0 + f1bq[0];
  zb[1 * HWc] = a1 + f1bq[1];
  zb[2 * HWc] = a2 + f1bq[2];
  zb[3 * HWc] = a3 + f1bq[3];
}

// ---------------- MLP: depthwise 3x3 (4 ch) + GELU ----------------
__global__ __launch_bounds__(256) void k_mlp_dw(const float* __restrict__ z4,
                                                const float* __restrict__ dwwq,
                                                const float* __restrict__ dwbq,
                                                float* __restrict__ z4b) {
  int tid = blockIdx.x * 256 + threadIdx.x;      // B*4*HW
  int hw = tid % HWc;
  int bj = tid / HWc;
  int j = bj % 4;
  int h = hw / Wc, w = hw % Wc;
  const float* zb = z4 + (size_t)bj * HWc;
  float s = 0.f;
#pragma unroll
  for (int ky = 0; ky < 3; ++ky) {
    int y = h + ky - 1;
    if ((unsigned)y >= (unsigned)Hc) continue;
#pragma unroll
    for (int kx = 0; kx < 3; ++kx) {
      int x = w + kx - 1;
      if ((unsigned)x >= (unsigned)Wc) continue;
      s += zb[y * Wc + x] * dwwq[j * 9 + ky * 3 + kx];
    }
  }
  z4b[tid] = gelu_exact(s + dwbq[j]);
}

// ---------------- MLP: f2 (4->96) + ls2 + residual add into out ----------------
__global__ __launch_bounds__(256) void k_mlp2(const float* __restrict__ z4b,
                                              const float* __restrict__ f2wq,
                                              const float* __restrict__ f2bq,
                                              const float* __restrict__ ls2q,
                                              float* __restrict__ out) {
  int pos = blockIdx.x * 256 + threadIdx.x;
  int bb = pos / HWc, hw = pos % HWc;
  const float* zb = z4b + (size_t)bb * 4 * HWc + hw;
  float z0 = zb[0 * HWc], z1 = zb[1 * HWc], z2 = zb[2 * HWc], z3 = zb[3 * HWc];
  float* ob = out + (size_t)bb * Cc * HWc + hw;
  for (int o = 0; o < Cc; ++o) {
    float s = f2bq[o] + z0 * f2wq[o * 4 + 0] + z1 * f2wq[o * 4 + 1]
                      + z2 * f2wq[o * 4 + 2] + z3 * f2wq[o * 4 + 3];
    ob[o * HWc] += ls2q[o] * s;
  }
}

}  // namespace

extern "C" void kernel_launch(void* const* d_in, const int* in_sizes, int n_in,
                              void* d_out, int out_size, void* d_ws, size_t ws_size,
                              hipStream_t stream) {
  (void)in_sizes; (void)n_in; (void)out_size; (void)ws_size;
  const float* x   = (const float*)d_in[0];
  const float* g1n = (const float*)d_in[1];
  const float* b1n = (const float*)d_in[2];
  const float* p1w = (const float*)d_in[3];
  const float* p1b = (const float*)d_in[4];
  const float* o0w = (const float*)d_in[5];
  const float* o0b = (const float*)d_in[6];
  const float* d0w = (const float*)d_in[7];
  const float* d0b = (const float*)d_in[8];
  const float* o1w = (const float*)d_in[9];
  const float* o1b = (const float*)d_in[10];
  const float* d1w = (const float*)d_in[11];
  const float* d1b = (const float*)d_in[12];
  const float* c1w = (const float*)d_in[13];
  const float* c1b = (const float*)d_in[14];
  const float* p2w = (const float*)d_in[15];
  const float* p2b = (const float*)d_in[16];
  const float* ls1 = (const float*)d_in[17];
  const float* g2n = (const float*)d_in[18];
  const float* b2n = (const float*)d_in[19];
  const float* f1w = (const float*)d_in[20];
  const float* f1b = (const float*)d_in[21];
  const float* dww = (const float*)d_in[22];
  const float* dwb = (const float*)d_in[23];
  const float* f2w = (const float*)d_in[24];
  const float* f2b = (const float*)d_in[25];
  const float* ls2 = (const float*)d_in[26];
  float* out = (float*)d_out;
  float* ws  = (float*)d_ws;

  const size_t NC = (size_t)Nc * Cc;            // 1,204,224 floats
  float* yln  = ws;
  float* u    = ws + 1 * NC;
  float* uT   = ws + 2 * NC;
  float* a0   = ws + 3 * NC;
  float* a0T  = ws + 4 * NC;
  float* a1   = ws + 5 * NC;
  float* A    = ws + 6 * NC;
  float* y2   = ws + 7 * NC;
  float* off0 = ws + 8 * NC;                    // B*50*HW = 627,200
  float* off1 = off0 + (size_t)Bc * 50 * HWc;   // B*98*HW = 1,229,312
  float* z4   = off1 + (size_t)Bc * 98 * HWc;   // B*4*HW
  float* z4b  = z4 + (size_t)Bc * 4 * HWc;

  dim3 b256(256, 1, 1), b64x4(64, 4, 1);

  hipLaunchKernelGGL(k_ln, dim3(Nc / 256), b256, 0, stream, x, g1n, b1n, yln);
  hipLaunchKernelGGL(k_pw96, dim3(Nc / 64), b64x4, 0, stream, yln, p1w, p1b, u, uT, 1);
  hipLaunchKernelGGL((k_conv<5, 1, 2, 50>), dim3(Nc / 64, 1), b64x4, 0, stream, u, o0w, o0b, off0);
  hipLaunchKernelGGL((k_deform<5, 1, 2>), dim3(Nc * 24 / 256), b256, 0, stream,
                     uT, off0, d0w, d0b, a0, a0T);
  hipLaunchKernelGGL((k_conv<7, 3, 9, 98>), dim3(Nc / 64, 2), b64x4, 0, stream, a0, o1w, o1b, off1);
  hipLaunchKernelGGL((k_deform<7, 3, 9>), dim3(Nc * 24 / 256), b256, 0, stream,
                     a0T, off1, d1w, d1b, a1, (float*)nullptr);
  hipLaunchKernelGGL(k_pw96, dim3(Nc / 64), b64x4, 0, stream, a1, c1w, c1b, A, (float*)nullptr, 0);
  hipLaunchKernelGGL(k_combine, dim3(Nc / 64), b64x4, 0, stream,
                     x, u, A, yln, p2w, p2b, ls1, y2, out);
  hipLaunchKernelGGL(k_mlp1, dim3(Nc / 256), b256, 0, stream, y2, g2n, b2n, f1w, f1b, z4);
  hipLaunchKernelGGL(k_mlp_dw, dim3(Nc * 4 / 256), b256, 0, stream, z4, dww, dwb, z4b);
  hipLaunchKernelGGL(k_mlp2, dim3(Nc / 256), b256, 0, stream, z4b, f2w, f2b, ls2, out);
}

// Round 2
// 488.546 us; speedup vs baseline: 13.1154x; 13.1154x over previous
//
#include <hip/hip_runtime.h>
#include <math.h>

namespace {

constexpr int Bc = 4, Cc = 96, Hc = 56, Wc = 56;
constexpr int HWc = Hc * Wc;       // 3136
constexpr int Nc  = Bc * HWc;      // 12544
constexpr float EPSc = 1e-5f;

typedef __attribute__((ext_vector_type(8))) short bf16x8;
typedef __attribute__((ext_vector_type(4))) float f32x4;

__device__ __forceinline__ unsigned short f2bf(float f) {
  union { float f; unsigned u; } x; x.f = f;
  unsigned r = x.u + 0x7fffu + ((x.u >> 16) & 1u);
  return (unsigned short)(r >> 16);
}
__device__ __forceinline__ float bf2f(unsigned short u) {
  union { unsigned u; float f; } x; x.u = (unsigned)u << 16; return x.f;
}
__device__ __forceinline__ float gelu_exact(float x) {
  return 0.5f * x * (1.0f + erff(x * 0.7071067811865475f));
}

// ---------------- LayerNorm over channel dim (NCHW) ----------------
__global__ __launch_bounds__(256) void k_ln(const float* __restrict__ x,
                                            const float* __restrict__ g,
                                            const float* __restrict__ b,
                                            float* __restrict__ out) {
  int pos = blockIdx.x * 256 + threadIdx.x;
  int bb = pos / HWc, hw = pos % HWc;
  const float* xb = x + (size_t)bb * Cc * HWc + hw;
  float s = 0.f, s2 = 0.f;
  for (int c = 0; c < Cc; ++c) { float v = xb[c * HWc]; s += v; s2 += v * v; }
  float mu  = s * (1.f / Cc);
  float var = fmaxf(s2 * (1.f / Cc) - mu * mu, 0.f);
  float rs  = rsqrtf(var + EPSc);
  float* ob = out + (size_t)bb * Cc * HWc + hw;
  for (int c = 0; c < Cc; ++c) {
    float v = xb[c * HWc];
    ob[c * HWc] = (v - mu) * rs * g[c] + b[c];
  }
}

// ---------------- 1x1 conv 96->96; optional GELU; optional padded-NHWC-bf16 out ----------------
template <int PADP, int WP>
__global__ __launch_bounds__(256) void k_pw96(const float* __restrict__ src,
                                              const float* __restrict__ wq,
                                              const float* __restrict__ bq,
                                              float* __restrict__ dst,
                                              unsigned short* __restrict__ padOut,
                                              int do_gelu) {
  int spos = blockIdx.x * 64 + threadIdx.x;
  int og = threadIdx.y;                          // wave-uniform
  int bb = spos / HWc, hw = spos % HWc;
  const float* sb = src + (size_t)bb * Cc * HWc + hw;
  float acc[24];
#pragma unroll
  for (int o = 0; o < 24; ++o) acc[o] = 0.f;
  for (int c = 0; c < Cc; ++c) {
    float v = sb[c * HWc];
    const float* wr = wq + (og * 24) * Cc + c;
#pragma unroll
    for (int o = 0; o < 24; ++o) acc[o] += v * wr[o * Cc];
  }
  float* db_ = dst + (size_t)bb * Cc * HWc + hw;
  float res[24];
#pragma unroll
  for (int o = 0; o < 24; ++o) {
    int oc = og * 24 + o;
    float r = acc[o] + bq[oc];
    if (do_gelu) r = gelu_exact(r);
    res[o] = r;
    db_[oc * HWc] = r;
  }
  if (padOut) {
    int h = hw / Wc, w = hw % Wc;
    unsigned short tmp[24];
#pragma unroll
    for (int o = 0; o < 24; ++o) tmp[o] = f2bf(res[o]);
    unsigned short* tb = padOut + (((size_t)bb * (Hc + 2 * PADP) + h + PADP) * WP + w + PADP) * Cc + og * 24;
#pragma unroll
    for (int q = 0; q < 3; ++q)
      *reinterpret_cast<bf16x8*>(tb + q * 8) = *reinterpret_cast<const bf16x8*>(tmp + q * 8);
  }
}

// ---------------- weight pack: W[o][c][ky][kx] -> frag layout bf16 ----------------
// wpk[((step*MT + mt)*64 + lane)*8 + j] = W[o = mt*16 + lane%16][k = step*32 + (lane/16)*8 + j]
// with k = p*96 + c (p = tap index row-major)
template <int K_, int MT, int P>
__global__ __launch_bounds__(256) void k_pack_w(const float* __restrict__ wsrc,
                                                unsigned short* __restrict__ wpk) {
  constexpr int TOTAL = K_ * K_ * 3 * MT * 512;
  int idx = blockIdx.x * 256 + threadIdx.x;
  if (idx >= TOTAL) return;
  int j    = idx & 7;
  int lane = (idx >> 3) & 63;
  int t    = idx >> 9;             // step*MT + mt
  int mt   = t % MT;
  int step = t / MT;
  int o = mt * 16 + (lane & 15);
  int k = step * 32 + ((lane >> 4) & 3) * 8 + j;
  int p = k / Cc, c = k % Cc;
  float v = 0.f;
  if (o < P) v = wsrc[(((size_t)o * Cc + c) * K_ + p / K_) * K_ + (p % K_)];
  wpk[idx] = f2bf(v);
}

// ---------------- implicit-GEMM MFMA conv: P outputs from padded NHWC bf16 ----------------
template <int K_, int DIL_, int MT, int P, int PADP, int WP>
__global__ __launch_bounds__(256) void k_conv_mfma(const unsigned short* __restrict__ inp,
                                                   const unsigned short* __restrict__ wpk,
                                                   const float* __restrict__ bq,
                                                   float* __restrict__ dst) {
  constexpr int KK = K_ * K_;
  constexpr int HP = Hc + 2 * PADP;
  int lane = threadIdx.x & 63;
  int wv = threadIdx.x >> 6;
  int n = blockIdx.x * 64 + wv * 16 + (lane & 15);
  int b = n / HWc, hw = n % HWc;
  int h = hw / Wc, w = hw % Wc;
  const unsigned short* ib = inp + ((size_t)b * HP * WP + (size_t)h * WP + w) * Cc + ((lane >> 4) & 3) * 8;
  const unsigned short* wl = wpk + (size_t)lane * 8;
  f32x4 acc[MT];
#pragma unroll
  for (int m = 0; m < MT; ++m) acc[m] = (f32x4){0.f, 0.f, 0.f, 0.f};
  for (int p = 0; p < KK; ++p) {
    const unsigned short* sp = ib + (size_t)((p / K_) * DIL_ * WP + (p % K_) * DIL_) * Cc;
#pragma unroll
    for (int cc = 0; cc < 3; ++cc) {
      bf16x8 bf = *reinterpret_cast<const bf16x8*>(sp + cc * 32);
      const unsigned short* wq_ = wl + (size_t)((p * 3 + cc) * MT) * 512;
#pragma unroll
      for (int m = 0; m < MT; ++m) {
        bf16x8 af = *reinterpret_cast<const bf16x8*>(wq_ + (size_t)m * 512);
        acc[m] = __builtin_amdgcn_mfma_f32_16x16x32_bf16(af, bf, acc[m], 0, 0, 0);
      }
    }
  }
  int orow = ((lane >> 4) & 3) * 4;
  float* db = dst + (size_t)b * P * HWc + hw;
#pragma unroll
  for (int m = 0; m < MT; ++m) {
#pragma unroll
    for (int j = 0; j < 4; ++j) {
      int o = m * 16 + orow + j;
      if (o < P) db[(size_t)o * HWc] = acc[m][j] + bq[o];
    }
  }
}

// ---------------- deformable depthwise sampling (bf16 padded NHWC src) ----------------
template <int K_, int DIL_, int PAD_, int IPADP, int IWP, int OPADP, int OWP>
__global__ __launch_bounds__(256) void k_deform(const unsigned short* __restrict__ srcT,
                                                const float* __restrict__ off,
                                                const float* __restrict__ dwq,
                                                const float* __restrict__ dbq,
                                                float* __restrict__ dst,
                                                unsigned short* __restrict__ dstPad) {
  constexpr int KK = K_ * K_;
  constexpr int IHP = Hc + 2 * IPADP;
  int tid = blockIdx.x * 256 + threadIdx.x;      // N*24 threads
  int cg = tid % 24;
  int pos = tid / 24;
  int c = cg * 4;
  int bb = pos / HWc, hw = pos % HWc;
  int h = hw / Wc, w = hw % Wc;
  const unsigned short* sb = srcT + (size_t)bb * IHP * IWP * Cc + c;
  const float* ob = off + (size_t)bb * (2 * KK) * HWc + hw;
  float ax = 0.f, ay = 0.f, az = 0.f, aw = 0.f;
  for (int p = 0; p < KK; ++p) {
    float oy = ob[(2 * p + 0) * HWc];
    float ox = ob[(2 * p + 1) * HWc];
    float py = (float)(h + (p / K_) * DIL_ - PAD_) + oy;
    float px = (float)(w + (p % K_) * DIL_ - PAD_) + ox;
    float y0f = floorf(py), x0f = floorf(px);
    float wy = py - y0f, wx = px - x0f;
    int y0 = (int)y0f, x0 = (int)x0f;
    float sx = 0.f, sy = 0.f, sz = 0.f, sw = 0.f;
#pragma unroll
    for (int dy = 0; dy < 2; ++dy) {
      int yi = y0 + dy;
      if ((unsigned)yi >= (unsigned)Hc) continue;
      float wyv = dy ? wy : 1.f - wy;
#pragma unroll
      for (int dx = 0; dx < 2; ++dx) {
        int xi = x0 + dx;
        if ((unsigned)xi >= (unsigned)Wc) continue;
        float wt = wyv * (dx ? wx : 1.f - wx);
        const uint2 v = *reinterpret_cast<const uint2*>(sb + ((size_t)(yi + IPADP) * IWP + (xi + IPADP)) * Cc);
        sx += wt * bf2f((unsigned short)(v.x & 0xffffu));
        sy += wt * bf2f((unsigned short)(v.x >> 16));
        sz += wt * bf2f((unsigned short)(v.y & 0xffffu));
        sw += wt * bf2f((unsigned short)(v.y >> 16));
      }
    }
    float d0 = dwq[(c + 0) * KK + p], d1 = dwq[(c + 1) * KK + p];
    float d2 = dwq[(c + 2) * KK + p], d3 = dwq[(c + 3) * KK + p];
    ax += sx * d0; ay += sy * d1; az += sz * d2; aw += sw * d3;
  }
  ax += dbq[c]; ay += dbq[c + 1]; az += dbq[c + 2]; aw += dbq[c + 3];
  if (dst) {
    float* d = dst + (size_t)bb * Cc * HWc + hw;
    d[(c + 0) * HWc] = ax; d[(c + 1) * HWc] = ay;
    d[(c + 2) * HWc] = az; d[(c + 3) * HWc] = aw;
  }
  if (dstPad) {
    unsigned short t4[4] = {f2bf(ax), f2bf(ay), f2bf(az), f2bf(aw)};
    unsigned short* tb = dstPad + (((size_t)bb * (Hc + 2 * OPADP) + h + OPADP) * OWP + w + OPADP) * Cc + c;
    *reinterpret_cast<uint2*>(tb) = *reinterpret_cast<const uint2*>(t4);
  }
}

// ---------------- gated projection + shortcut + ls1 + residual ----------------
__global__ __launch_bounds__(256) void k_combine(const float* __restrict__ x,
                                                 const float* __restrict__ u,
                                                 const float* __restrict__ a,
                                                 const float* __restrict__ yln,
                                                 const float* __restrict__ wq,
                                                 const float* __restrict__ bq,
                                                 const float* __restrict__ ls1q,
                                                 float* __restrict__ y2,
                                                 float* __restrict__ xo) {
  int spos = blockIdx.x * 64 + threadIdx.x;
  int og = threadIdx.y;
  int bb = spos / HWc, hw = spos % HWc;
  size_t base = (size_t)bb * Cc * HWc + hw;
  float acc[24];
#pragma unroll
  for (int o = 0; o < 24; ++o) acc[o] = 0.f;
  for (int c = 0; c < Cc; ++c) {
    float v = u[base + (size_t)c * HWc] * a[base + (size_t)c * HWc];
    const float* wr = wq + (og * 24) * Cc + c;
#pragma unroll
    for (int o = 0; o < 24; ++o) acc[o] += v * wr[o * Cc];
  }
#pragma unroll
  for (int o = 0; o < 24; ++o) {
    int oc = og * 24 + o;
    float t = acc[o] + bq[oc] + yln[base + (size_t)oc * HWc];
    float yv = ls1q[oc] * t;
    y2[base + (size_t)oc * HWc] = yv;
    xo[base + (size_t)oc * HWc] = x[base + (size_t)oc * HWc] + yv;
  }
}

// ---------------- MLP: LN2 + f1 (96->4) ----------------
__global__ __launch_bounds__(256) void k_mlp1(const float* __restrict__ y2,
                                              const float* __restrict__ g,
                                              const float* __restrict__ b,
                                              const float* __restrict__ f1wq,
                                              const float* __restrict__ f1bq,
                                              float* __restrict__ z4) {
  int pos = blockIdx.x * 256 + threadIdx.x;
  int bb = pos / HWc, hw = pos % HWc;
  const float* yb = y2 + (size_t)bb * Cc * HWc + hw;
  float s = 0.f, s2 = 0.f;
  for (int c = 0; c < Cc; ++c) { float v = yb[c * HWc]; s += v; s2 += v * v; }
  float mu  = s * (1.f / Cc);
  float var = fmaxf(s2 * (1.f / Cc) - mu * mu, 0.f);
  float rs  = rsqrtf(var + EPSc);
  float a0 = 0.f, a1 = 0.f, a2 = 0.f, a3 = 0.f;
  for (int c = 0; c < Cc; ++c) {
    float t = (yb[c * HWc] - mu) * rs * g[c] + b[c];
    a0 += t * f1wq[0 * Cc + c];
    a1 += t * f1wq[1 * Cc + c];
    a2 += t * f1wq[2 * Cc + c];
    a3 += t * f1wq[3 * Cc + c];
  }
  float* zb = z4 + (size_t)bb * 4 * HWc + hw;
  zb[0 * HWc] = a0 + f1bq[0];
  zb[1 * HWc] = a1 + f1bq[1];
  zb[2 * HWc] = a2 + f1bq[2];
  zb[3 * HWc] = a3 + f1bq[3];
}

// ---------------- MLP: depthwise 3x3 (4 ch) + GELU ----------------
__global__ __launch_bounds__(256) void k_mlp_dw(const float* __restrict__ z4,
                                                const float* __restrict__ dwwq,
                                                const float* __restrict__ dwbq,
                                                float* __restrict__ z4b) {
  int tid = blockIdx.x * 256 + threadIdx.x;
  int hw = tid % HWc;
  int bj = tid / HWc;
  int j = bj % 4;
  int h = hw / Wc, w = hw % Wc;
  const float* zb = z4 + (size_t)bj * HWc;
  float s = 0.f;
#pragma unroll
  for (int ky = 0; ky < 3; ++ky) {
    int y = h + ky - 1;
    if ((unsigned)y >= (unsigned)Hc) continue;
#pragma unroll
    for (int kx = 0; kx < 3; ++kx) {
      int x = w + kx - 1;
      if ((unsigned)x >= (unsigned)Wc) continue;
      s += zb[y * Wc + x] * dwwq[j * 9 + ky * 3 + kx];
    }
  }
  z4b[tid] = gelu_exact(s + dwbq[j]);
}

// ---------------- MLP: f2 (4->96) + ls2 + residual add into out ----------------
__global__ __launch_bounds__(256) void k_mlp2(const float* __restrict__ z4b,
                                              const float* __restrict__ f2wq,
                                              const float* __restrict__ f2bq,
                                              const float* __restrict__ ls2q,
                                              float* __restrict__ out) {
  int pos = blockIdx.x * 256 + threadIdx.x;
  int bb = pos / HWc, hw = pos % HWc;
  const float* zb = z4b + (size_t)bb * 4 * HWc + hw;
  float z0 = zb[0 * HWc], z1 = zb[1 * HWc], z2 = zb[2 * HWc], z3 = zb[3 * HWc];
  float* ob = out + (size_t)bb * Cc * HWc + hw;
  for (int o = 0; o < Cc; ++o) {
    float s = f2bq[o] + z0 * f2wq[o * 4 + 0] + z1 * f2wq[o * 4 + 1]
                      + z2 * f2wq[o * 4 + 2] + z3 * f2wq[o * 4 + 3];
    ob[o * HWc] += ls2q[o] * s;
  }
}

}  // namespace

extern "C" void kernel_launch(void* const* d_in, const int* in_sizes, int n_in,
                              void* d_out, int out_size, void* d_ws, size_t ws_size,
                              hipStream_t stream) {
  (void)in_sizes; (void)n_in; (void)out_size; (void)ws_size;
  const float* x   = (const float*)d_in[0];
  const float* g1n = (const float*)d_in[1];
  const float* b1n = (const float*)d_in[2];
  const float* p1w = (const float*)d_in[3];
  const float* p1b = (const float*)d_in[4];
  const float* o0w = (const float*)d_in[5];
  const float* o0b = (const float*)d_in[6];
  const float* d0w = (const float*)d_in[7];
  const float* d0b = (const float*)d_in[8];
  const float* o1w = (const float*)d_in[9];
  const float* o1b = (const float*)d_in[10];
  const float* d1w = (const float*)d_in[11];
  const float* d1b = (const float*)d_in[12];
  const float* c1w = (const float*)d_in[13];
  const float* c1b = (const float*)d_in[14];
  const float* p2w = (const float*)d_in[15];
  const float* p2b = (const float*)d_in[16];
  const float* ls1 = (const float*)d_in[17];
  const float* g2n = (const float*)d_in[18];
  const float* b2n = (const float*)d_in[19];
  const float* f1w = (const float*)d_in[20];
  const float* f1b = (const float*)d_in[21];
  const float* dww = (const float*)d_in[22];
  const float* dwb = (const float*)d_in[23];
  const float* f2w = (const float*)d_in[24];
  const float* f2b = (const float*)d_in[25];
  const float* ls2 = (const float*)d_in[26];
  float* out = (float*)d_out;
  float* ws  = (float*)d_ws;

  const size_t NC = (size_t)Nc * Cc;
  float* yln  = ws;                                  size_t o_ = NC;
  float* u    = ws + o_;                             o_ += NC;
  float* A    = ws + o_;                             o_ += NC;
  float* y2   = ws + o_;                             o_ += NC;
  float* a1   = ws + o_;                             o_ += NC;
  float* off0 = ws + o_;                             o_ += (size_t)Bc * 50 * HWc;
  float* off1 = ws + o_;                             o_ += (size_t)Bc * 98 * HWc;
  float* z4   = ws + o_;                             o_ += (size_t)Bc * 4 * HWc;
  float* z4b  = ws + o_;                             o_ += (size_t)Bc * 4 * HWc;
  unsigned short* u_pad  = (unsigned short*)(ws + o_); o_ += (size_t)Bc * 60 * 60 * Cc / 2;
  unsigned short* a0_pad = (unsigned short*)(ws + o_); o_ += (size_t)Bc * 74 * 74 * Cc / 2;
  unsigned short* wpk0   = (unsigned short*)(ws + o_); o_ += (size_t)25 * 3 * 4 * 512 / 2;
  unsigned short* wpk1   = (unsigned short*)(ws + o_); o_ += (size_t)49 * 3 * 7 * 512 / 2;

  dim3 b256(256, 1, 1), b64x4(64, 4, 1);

  hipMemsetAsync(u_pad, 0, (size_t)Bc * 60 * 60 * Cc * sizeof(unsigned short), stream);
  hipMemsetAsync(a0_pad, 0, (size_t)Bc * 74 * 74 * Cc * sizeof(unsigned short), stream);
  hipLaunchKernelGGL((k_pack_w<5, 4, 50>), dim3((25 * 3 * 4 * 512 + 255) / 256), b256, 0, stream, o0w, wpk0);
  hipLaunchKernelGGL((k_pack_w<7, 7, 98>), dim3((49 * 3 * 7 * 512 + 255) / 256), b256, 0, stream, o1w, wpk1);

  hipLaunchKernelGGL(k_ln, dim3(Nc / 256), b256, 0, stream, x, g1n, b1n, yln);
  hipLaunchKernelGGL((k_pw96<2, 60>), dim3(Nc / 64), b64x4, 0, stream, yln, p1w, p1b, u, u_pad, 1);
  hipLaunchKernelGGL((k_conv_mfma<5, 1, 4, 50, 2, 60>), dim3(Nc / 64), b256, 0, stream,
                     u_pad, wpk0, o0b, off0);
  hipLaunchKernelGGL((k_deform<5, 1, 2, 2, 60, 9, 74>), dim3(Nc * 24 / 256), b256, 0, stream,
                     u_pad, off0, d0w, d0b, (float*)nullptr, a0_pad);
  hipLaunchKernelGGL((k_conv_mfma<7, 3, 7, 98, 9, 74>), dim3(Nc / 64), b256, 0, stream,
                     a0_pad, wpk1, o1b, off1);
  hipLaunchKernelGGL((k_deform<7, 3, 9, 9, 74, 9, 74>), dim3(Nc * 24 / 256), b256, 0, stream,
                     a0_pad, off1, d1w, d1b, a1, (unsigned short*)nullptr);
  hipLaunchKernelGGL((k_pw96<2, 60>), dim3(Nc / 64), b64x4, 0, stream, a1, c1w, c1b, A,
                     (unsigned short*)nullptr, 0);
  hipLaunchKernelGGL(k_combine, dim3(Nc / 64), b64x4, 0, stream,
                     x, u, A, yln, p2w, p2b, ls1, y2, out);
  hipLaunchKernelGGL(k_mlp1, dim3(Nc / 256), b256, 0, stream, y2, g2n, b2n, f1w, f1b, z4);
  hipLaunchKernelGGL(k_mlp_dw, dim3(Nc * 4 / 256), b256, 0, stream, z4, dww, dwb, z4b);
  hipLaunchKernelGGL(k_mlp2, dim3(Nc / 256), b256, 0, stream, z4b, f2w, f2b, ls2, out);
}

// Round 3
// 384.243 us; speedup vs baseline: 16.6756x; 1.2715x over previous
//
#include <hip/hip_runtime.h>
#include <math.h>

namespace {

constexpr int Bc = 4, Cc = 96, Hc = 56, Wc = 56;
constexpr int HWc = Hc * Wc;       // 3136
constexpr int Nc  = Bc * HWc;      // 12544
constexpr float EPSc = 1e-5f;

typedef __attribute__((ext_vector_type(8))) short bf16x8;
typedef __attribute__((ext_vector_type(4))) float f32x4;

__device__ __forceinline__ unsigned short f2bf(float f) {
  union { float f; unsigned u; } x; x.f = f;
  unsigned r = x.u + 0x7fffu + ((x.u >> 16) & 1u);
  return (unsigned short)(r >> 16);
}
__device__ __forceinline__ float bf2f(unsigned short u) {
  union { unsigned u; float f; } x; x.u = (unsigned)u << 16; return x.f;
}
__device__ __forceinline__ float gelu_exact(float x) {
  return 0.5f * x * (1.0f + erff(x * 0.7071067811865475f));
}

// ---------------- LayerNorm over channel dim (NCHW) ----------------
__global__ __launch_bounds__(256) void k_ln(const float* __restrict__ x,
                                            const float* __restrict__ g,
                                            const float* __restrict__ b,
                                            float* __restrict__ out) {
  int pos = blockIdx.x * 256 + threadIdx.x;
  int bb = pos / HWc, hw = pos % HWc;
  const float* xb = x + (size_t)bb * Cc * HWc + hw;
  float s = 0.f, s2 = 0.f;
  for (int c = 0; c < Cc; ++c) { float v = xb[c * HWc]; s += v; s2 += v * v; }
  float mu  = s * (1.f / Cc);
  float var = fmaxf(s2 * (1.f / Cc) - mu * mu, 0.f);
  float rs  = rsqrtf(var + EPSc);
  float* ob = out + (size_t)bb * Cc * HWc + hw;
  for (int c = 0; c < Cc; ++c) {
    float v = xb[c * HWc];
    ob[c * HWc] = (v - mu) * rs * g[c] + b[c];
  }
}

// ---------------- 1x1 conv 96->96; optional GELU; optional padded-NHWC-bf16 out ----------------
template <int PADP, int WP>
__global__ __launch_bounds__(256) void k_pw96(const float* __restrict__ src,
                                              const float* __restrict__ wq,
                                              const float* __restrict__ bq,
                                              float* __restrict__ dst,
                                              unsigned short* __restrict__ padOut,
                                              int do_gelu) {
  int spos = blockIdx.x * 64 + threadIdx.x;
  int og = threadIdx.y;                          // wave-uniform
  int bb = spos / HWc, hw = spos % HWc;
  const float* sb = src + (size_t)bb * Cc * HWc + hw;
  float acc[24];
#pragma unroll
  for (int o = 0; o < 24; ++o) acc[o] = 0.f;
  for (int c = 0; c < Cc; ++c) {
    float v = sb[c * HWc];
    const float* wr = wq + (og * 24) * Cc + c;
#pragma unroll
    for (int o = 0; o < 24; ++o) acc[o] += v * wr[o * Cc];
  }
  float* db_ = dst + (size_t)bb * Cc * HWc + hw;
  float res[24];
#pragma unroll
  for (int o = 0; o < 24; ++o) {
    int oc = og * 24 + o;
    float r = acc[o] + bq[oc];
    if (do_gelu) r = gelu_exact(r);
    res[o] = r;
    db_[oc * HWc] = r;
  }
  if (padOut) {
    int h = hw / Wc, w = hw % Wc;
    unsigned short tmp[24];
#pragma unroll
    for (int o = 0; o < 24; ++o) tmp[o] = f2bf(res[o]);
    unsigned short* tb = padOut + (((size_t)bb * (Hc + 2 * PADP) + h + PADP) * WP + w + PADP) * Cc + og * 24;
#pragma unroll
    for (int q = 0; q < 3; ++q)
      *reinterpret_cast<bf16x8*>(tb + q * 8) = *reinterpret_cast<const bf16x8*>(tmp + q * 8);
  }
}

// ---------------- weight pack: W[o][c][ky][kx] -> frag layout bf16 ----------------
template <int K_, int MT, int P>
__global__ __launch_bounds__(256) void k_pack_w(const float* __restrict__ wsrc,
                                                unsigned short* __restrict__ wpk) {
  constexpr int TOTAL = K_ * K_ * 3 * MT * 512;
  int idx = blockIdx.x * 256 + threadIdx.x;
  if (idx >= TOTAL) return;
  int j    = idx & 7;
  int lane = (idx >> 3) & 63;
  int t    = idx >> 9;             // step*MT + mt
  int mt   = t % MT;
  int step = t / MT;
  int o = mt * 16 + (lane & 15);
  int k = step * 32 + ((lane >> 4) & 3) * 8 + j;
  int p = k / Cc, c = k % Cc;
  float v = 0.f;
  if (o < P) v = wsrc[(((size_t)o * Cc + c) * K_ + p / K_) * K_ + (p % K_)];
  wpk[idx] = f2bf(v);
}

// ---------------- depthwise weight transpose [C][KK] -> [KK][C] ----------------
__global__ __launch_bounds__(256) void k_pack_dwt(const float* __restrict__ dwsrc,
                                                  float* __restrict__ dwt, int KK) {
  int idx = blockIdx.x * 256 + threadIdx.x;
  if (idx >= KK * Cc) return;
  int p = idx / Cc, c = idx % Cc;
  dwt[idx] = dwsrc[c * KK + p];
}

// ---------------- implicit-GEMM MFMA conv -> transposed offset out [pos][PSTR] ----------------
template <int K_, int DIL_, int MT, int P, int PADP, int WP, int PSTR>
__global__ __launch_bounds__(256) void k_conv_mfma(const unsigned short* __restrict__ inp,
                                                   const unsigned short* __restrict__ wpk,
                                                   const float* __restrict__ bq,
                                                   float* __restrict__ dstT) {
  constexpr int KK = K_ * K_;
  constexpr int HP = Hc + 2 * PADP;
  int lane = threadIdx.x & 63;
  int wv = threadIdx.x >> 6;
  int n = blockIdx.x * 64 + wv * 16 + (lane & 15);
  int b = n / HWc, hw = n % HWc;
  int h = hw / Wc, w = hw % Wc;
  const unsigned short* ib = inp + ((size_t)b * HP * WP + (size_t)h * WP + w) * Cc + ((lane >> 4) & 3) * 8;
  const unsigned short* wl = wpk + (size_t)lane * 8;
  f32x4 acc[MT];
#pragma unroll
  for (int m = 0; m < MT; ++m) acc[m] = (f32x4){0.f, 0.f, 0.f, 0.f};
  for (int p = 0; p < KK; ++p) {
    const unsigned short* sp = ib + (size_t)((p / K_) * DIL_ * WP + (p % K_) * DIL_) * Cc;
#pragma unroll
    for (int cc = 0; cc < 3; ++cc) {
      bf16x8 bf = *reinterpret_cast<const bf16x8*>(sp + cc * 32);
      const unsigned short* wq_ = wl + (size_t)((p * 3 + cc) * MT) * 512;
#pragma unroll
      for (int m = 0; m < MT; ++m) {
        bf16x8 af = *reinterpret_cast<const bf16x8*>(wq_ + (size_t)m * 512);
        acc[m] = __builtin_amdgcn_mfma_f32_16x16x32_bf16(af, bf, acc[m], 0, 0, 0);
      }
    }
  }
  int orow = ((lane >> 4) & 3) * 4;
  float* db = dstT + (size_t)n * PSTR;
#pragma unroll
  for (int m = 0; m < MT; ++m) {
    float4 st;
#pragma unroll
    for (int j = 0; j < 4; ++j) {
      int o = m * 16 + orow + j;
      float bias = (o < P) ? bq[o] : 0.f;
      ((float*)&st)[j] = acc[m][j] + bias;
    }
    *reinterpret_cast<float4*>(db + m * 16 + orow) = st;
  }
}

// ---------------- deformable depthwise sampling (bf16 padded NHWC src) ----------------
// offT: [pos][PSTR] transposed offsets; dwt: [KK][C]
template <int K_, int DIL_, int PAD_, int IPADP, int IWP, int OPADP, int OWP, int PSTR>
__global__ __launch_bounds__(256) void k_deform(const unsigned short* __restrict__ srcT,
                                                const float* __restrict__ offT,
                                                const float* __restrict__ dwt,
                                                const float* __restrict__ dbq,
                                                float* __restrict__ dst,
                                                unsigned short* __restrict__ dstPad) {
  constexpr int KK = K_ * K_;
  constexpr int KK4 = KK & ~3;
  constexpr int IHP = Hc + 2 * IPADP;
  int tid = blockIdx.x * 256 + threadIdx.x;      // N*24 threads
  int cg = tid % 24;
  int pos = tid / 24;
  int c = cg * 4;
  int bb = pos / HWc, hw = pos % HWc;
  int h = hw / Wc, w = hw % Wc;
  const unsigned short* sb = srcT + (size_t)bb * IHP * IWP * Cc + c;
  const float* ob = offT + (size_t)pos * PSTR;
  float ax = 0.f, ay = 0.f, az = 0.f, aw = 0.f;

  for (int pg = 0; pg < KK4; pg += 4) {
    float4 o01 = *reinterpret_cast<const float4*>(ob + 2 * pg);
    float4 o23 = *reinterpret_cast<const float4*>(ob + 2 * pg + 4);
    float oyv[4] = {o01.x, o01.z, o23.x, o23.z};
    float oxv[4] = {o01.y, o01.w, o23.y, o23.w};
    uint2 v[4][4];
    float wt[4][4];
#pragma unroll
    for (int i = 0; i < 4; ++i) {
      int p = pg + i;
      float py = (float)(h + (p / K_) * DIL_ - PAD_) + oyv[i];
      float px = (float)(w + (p % K_) * DIL_ - PAD_) + oxv[i];
      float y0f = floorf(py), x0f = floorf(px);
      float wy = py - y0f, wx = px - x0f;
      int y0 = (int)y0f, x0 = (int)x0f;
#pragma unroll
      for (int dy = 0; dy < 2; ++dy) {
        int yi = y0 + dy;
        bool yv = (unsigned)yi < (unsigned)Hc;
        int yc = min(max(yi, 0), Hc - 1);
        float wyv = dy ? wy : 1.f - wy;
#pragma unroll
        for (int dx = 0; dx < 2; ++dx) {
          int xi = x0 + dx;
          bool xv = (unsigned)xi < (unsigned)Wc;
          int xc = min(max(xi, 0), Wc - 1);
          wt[i][dy * 2 + dx] = (yv && xv) ? wyv * (dx ? wx : 1.f - wx) : 0.f;
          v[i][dy * 2 + dx] = *reinterpret_cast<const uint2*>(
              sb + ((size_t)(yc + IPADP) * IWP + (xc + IPADP)) * Cc);
        }
      }
    }
#pragma unroll
    for (int i = 0; i < 4; ++i) {
      int p = pg + i;
      float4 d = *reinterpret_cast<const float4*>(dwt + (size_t)p * Cc + c);
      float sx = 0.f, sy = 0.f, sz = 0.f, sw = 0.f;
#pragma unroll
      for (int q = 0; q < 4; ++q) {
        float wq_ = wt[i][q];
        sx += wq_ * bf2f((unsigned short)(v[i][q].x & 0xffffu));
        sy += wq_ * bf2f((unsigned short)(v[i][q].x >> 16));
        sz += wq_ * bf2f((unsigned short)(v[i][q].y & 0xffffu));
        sw += wq_ * bf2f((unsigned short)(v[i][q].y >> 16));
      }
      ax += sx * d.x; ay += sy * d.y; az += sz * d.z; aw += sw * d.w;
    }
  }
  // tail tap (KK % 4 == 1 for K=5,7)
  {
    int p = KK - 1;
    float oy = ob[2 * p], ox = ob[2 * p + 1];
    float py = (float)(h + (p / K_) * DIL_ - PAD_) + oy;
    float px = (float)(w + (p % K_) * DIL_ - PAD_) + ox;
    float y0f = floorf(py), x0f = floorf(px);
    float wy = py - y0f, wx = px - x0f;
    int y0 = (int)y0f, x0 = (int)x0f;
    uint2 v[4]; float wt[4];
#pragma unroll
    for (int dy = 0; dy < 2; ++dy) {
      int yi = y0 + dy;
      bool yv = (unsigned)yi < (unsigned)Hc;
      int yc = min(max(yi, 0), Hc - 1);
      float wyv = dy ? wy : 1.f - wy;
#pragma unroll
      for (int dx = 0; dx < 2; ++dx) {
        int xi = x0 + dx;
        bool xv = (unsigned)xi < (unsigned)Wc;
        int xc = min(max(xi, 0), Wc - 1);
        wt[dy * 2 + dx] = (yv && xv) ? wyv * (dx ? wx : 1.f - wx) : 0.f;
        v[dy * 2 + dx] = *reinterpret_cast<const uint2*>(
            sb + ((size_t)(yc + IPADP) * IWP + (xc + IPADP)) * Cc);
      }
    }
    float4 d = *reinterpret_cast<const float4*>(dwt + (size_t)p * Cc + c);
    float sx = 0.f, sy = 0.f, sz = 0.f, sw = 0.f;
#pragma unroll
    for (int q = 0; q < 4; ++q) {
      sx += wt[q] * bf2f((unsigned short)(v[q].x & 0xffffu));
      sy += wt[q] * bf2f((unsigned short)(v[q].x >> 16));
      sz += wt[q] * bf2f((unsigned short)(v[q].y & 0xffffu));
      sw += wt[q] * bf2f((unsigned short)(v[q].y >> 16));
    }
    ax += sx * d.x; ay += sy * d.y; az += sz * d.z; aw += sw * d.w;
  }

  ax += dbq[c]; ay += dbq[c + 1]; az += dbq[c + 2]; aw += dbq[c + 3];
  if (dst) {
    float* d = dst + (size_t)bb * Cc * HWc + hw;
    d[(c + 0) * HWc] = ax; d[(c + 1) * HWc] = ay;
    d[(c + 2) * HWc] = az; d[(c + 3) * HWc] = aw;
  }
  if (dstPad) {
    unsigned short t4[4] = {f2bf(ax), f2bf(ay), f2bf(az), f2bf(aw)};
    unsigned short* tb = dstPad + (((size_t)bb * (Hc + 2 * OPADP) + h + OPADP) * OWP + w + OPADP) * Cc + c;
    *reinterpret_cast<uint2*>(tb) = *reinterpret_cast<const uint2*>(t4);
  }
}

// ---------------- gated projection + shortcut + ls1 + residual ----------------
__global__ __launch_bounds__(256) void k_combine(const float* __restrict__ x,
                                                 const float* __restrict__ u,
                                                 const float* __restrict__ a,
                                                 const float* __restrict__ yln,
                                                 const float* __restrict__ wq,
                                                 const float* __restrict__ bq,
                                                 const float* __restrict__ ls1q,
                                                 float* __restrict__ y2,
                                                 float* __restrict__ xo) {
  int spos = blockIdx.x * 64 + threadIdx.x;
  int og = threadIdx.y;
  int bb = spos / HWc, hw = spos % HWc;
  size_t base = (size_t)bb * Cc * HWc + hw;
  float acc[24];
#pragma unroll
  for (int o = 0; o < 24; ++o) acc[o] = 0.f;
  for (int c = 0; c < Cc; ++c) {
    float v = u[base + (size_t)c * HWc] * a[base + (size_t)c * HWc];
    const float* wr = wq + (og * 24) * Cc + c;
#pragma unroll
    for (int o = 0; o < 24; ++o) acc[o] += v * wr[o * Cc];
  }
#pragma unroll
  for (int o = 0; o < 24; ++o) {
    int oc = og * 24 + o;
    float t = acc[o] + bq[oc] + yln[base + (size_t)oc * HWc];
    float yv = ls1q[oc] * t;
    y2[base + (size_t)oc * HWc] = yv;
    xo[base + (size_t)oc * HWc] = x[base + (size_t)oc * HWc] + yv;
  }
}

// ---------------- MLP: LN2 + f1 (96->4) ----------------
__global__ __launch_bounds__(256) void k_mlp1(const float* __restrict__ y2,
                                              const float* __restrict__ g,
                                              const float* __restrict__ b,
                                              const float* __restrict__ f1wq,
                                              const float* __restrict__ f1bq,
                                              float* __restrict__ z4) {
  int pos = blockIdx.x * 256 + threadIdx.x;
  int bb = pos / HWc, hw = pos % HWc;
  const float* yb = y2 + (size_t)bb * Cc * HWc + hw;
  float s = 0.f, s2 = 0.f;
  for (int c = 0; c < Cc; ++c) { float v = yb[c * HWc]; s += v; s2 += v * v; }
  float mu  = s * (1.f / Cc);
  float var = fmaxf(s2 * (1.f / Cc) - mu * mu, 0.f);
  float rs  = rsqrtf(var + EPSc);
  float a0 = 0.f, a1 = 0.f, a2 = 0.f, a3 = 0.f;
  for (int c = 0; c < Cc; ++c) {
    float t = (yb[c * HWc] - mu) * rs * g[c] + b[c];
    a0 += t * f1wq[0 * Cc + c];
    a1 += t * f1wq[1 * Cc + c];
    a2 += t * f1wq[2 * Cc + c];
    a3 += t * f1wq[3 * Cc + c];
  }
  float* zb = z4 + (size_t)bb * 4 * HWc + hw;
  zb[0 * HWc] = a0 + f1bq[0];
  zb[1 * HWc] = a1 + f1bq[1];
  zb[2 * HWc] = a2 + f1bq[2];
  zb[3 * HWc] = a3 + f1bq[3];
}

// ---------------- MLP: depthwise 3x3 (4 ch) + GELU ----------------
__global__ __launch_bounds__(256) void k_mlp_dw(const float* __restrict__ z4,
                                                const float* __restrict__ dwwq,
                                                const float* __restrict__ dwbq,
                                                float* __restrict__ z4b) {
  int tid = blockIdx.x * 256 + threadIdx.x;
  int hw = tid % HWc;
  int bj = tid / HWc;
  int j = bj % 4;
  int h = hw / Wc, w = hw % Wc;
  const float* zb = z4 + (size_t)bj * HWc;
  float s = 0.f;
#pragma unroll
  for (int ky = 0; ky < 3; ++ky) {
    int y = h + ky - 1;
    if ((unsigned)y >= (unsigned)Hc) continue;
#pragma unroll
    for (int kx = 0; kx < 3; ++kx) {
      int x = w + kx - 1;
      if ((unsigned)x >= (unsigned)Wc) continue;
      s += zb[y * Wc + x] * dwwq[j * 9 + ky * 3 + kx];
    }
  }
  z4b[tid] = gelu_exact(s + dwbq[j]);
}

// ---------------- MLP: f2 (4->96) + ls2 + residual add into out ----------------
__global__ __launch_bounds__(256) void k_mlp2(const float* __restrict__ z4b,
                                              const float* __restrict__ f2wq,
                                              const float* __restrict__ f2bq,
                                              const float* __restrict__ ls2q,
                                              float* __restrict__ out) {
  int pos = blockIdx.x * 256 + threadIdx.x;
  int bb = pos / HWc, hw = pos % HWc;
  const float* zb = z4b + (size_t)bb * 4 * HWc + hw;
  float z0 = zb[0 * HWc], z1 = zb[1 * HWc], z2 = zb[2 * HWc], z3 = zb[3 * HWc];
  float* ob = out + (size_t)bb * Cc * HWc + hw;
  for (int o = 0; o < Cc; ++o) {
    float s = f2bq[o] + z0 * f2wq[o * 4 + 0] + z1 * f2wq[o * 4 + 1]
                      + z2 * f2wq[o * 4 + 2] + z3 * f2wq[o * 4 + 3];
    ob[o * HWc] += ls2q[o] * s;
  }
}

}  // namespace

extern "C" void kernel_launch(void* const* d_in, const int* in_sizes, int n_in,
                              void* d_out, int out_size, void* d_ws, size_t ws_size,
                              hipStream_t stream) {
  (void)in_sizes; (void)n_in; (void)out_size; (void)ws_size;
  const float* x   = (const float*)d_in[0];
  const float* g1n = (const float*)d_in[1];
  const float* b1n = (const float*)d_in[2];
  const float* p1w = (const float*)d_in[3];
  const float* p1b = (const float*)d_in[4];
  const float* o0w = (const float*)d_in[5];
  const float* o0b = (const float*)d_in[6];
  const float* d0w = (const float*)d_in[7];
  const float* d0b = (const float*)d_in[8];
  const float* o1w = (const float*)d_in[9];
  const float* o1b = (const float*)d_in[10];
  const float* d1w = (const float*)d_in[11];
  const float* d1b = (const float*)d_in[12];
  const float* c1w = (const float*)d_in[13];
  const float* c1b = (const float*)d_in[14];
  const float* p2w = (const float*)d_in[15];
  const float* p2b = (const float*)d_in[16];
  const float* ls1 = (const float*)d_in[17];
  const float* g2n = (const float*)d_in[18];
  const float* b2n = (const float*)d_in[19];
  const float* f1w = (const float*)d_in[20];
  const float* f1b = (const float*)d_in[21];
  const float* dww = (const float*)d_in[22];
  const float* dwb = (const float*)d_in[23];
  const float* f2w = (const float*)d_in[24];
  const float* f2b = (const float*)d_in[25];
  const float* ls2 = (const float*)d_in[26];
  float* out = (float*)d_out;
  float* ws  = (float*)d_ws;

  const size_t NC = (size_t)Nc * Cc;
  float* yln   = ws;                                  size_t o_ = NC;
  float* u     = ws + o_;                             o_ += NC;
  float* A     = ws + o_;                             o_ += NC;
  float* y2    = ws + o_;                             o_ += NC;
  float* a1    = ws + o_;                             o_ += NC;
  float* off0t = ws + o_;                             o_ += (size_t)Nc * 64;
  float* off1t = ws + o_;                             o_ += (size_t)Nc * 112;
  float* z4    = ws + o_;                             o_ += (size_t)Bc * 4 * HWc;
  float* z4b   = ws + o_;                             o_ += (size_t)Bc * 4 * HWc;
  float* dwt0  = ws + o_;                             o_ += 25 * Cc;
  float* dwt1  = ws + o_;                             o_ += 49 * Cc;
  unsigned short* u_pad  = (unsigned short*)(ws + o_); o_ += (size_t)Bc * 60 * 60 * Cc / 2;
  unsigned short* a0_pad = (unsigned short*)(ws + o_); o_ += (size_t)Bc * 74 * 74 * Cc / 2;
  unsigned short* wpk0   = (unsigned short*)(ws + o_); o_ += (size_t)25 * 3 * 4 * 512 / 2;
  unsigned short* wpk1   = (unsigned short*)(ws + o_); o_ += (size_t)49 * 3 * 7 * 512 / 2;

  dim3 b256(256, 1, 1), b64x4(64, 4, 1);

  hipMemsetAsync(u_pad, 0, (size_t)Bc * 60 * 60 * Cc * sizeof(unsigned short), stream);
  hipMemsetAsync(a0_pad, 0, (size_t)Bc * 74 * 74 * Cc * sizeof(unsigned short), stream);
  hipLaunchKernelGGL((k_pack_w<5, 4, 50>), dim3((25 * 3 * 4 * 512 + 255) / 256), b256, 0, stream, o0w, wpk0);
  hipLaunchKernelGGL((k_pack_w<7, 7, 98>), dim3((49 * 3 * 7 * 512 + 255) / 256), b256, 0, stream, o1w, wpk1);
  hipLaunchKernelGGL(k_pack_dwt, dim3((25 * Cc + 255) / 256), b256, 0, stream, d0w, dwt0, 25);
  hipLaunchKernelGGL(k_pack_dwt, dim3((49 * Cc + 255) / 256), b256, 0, stream, d1w, dwt1, 49);

  hipLaunchKernelGGL(k_ln, dim3(Nc / 256), b256, 0, stream, x, g1n, b1n, yln);
  hipLaunchKernelGGL((k_pw96<2, 60>), dim3(Nc / 64), b64x4, 0, stream, yln, p1w, p1b, u, u_pad, 1);
  hipLaunchKernelGGL((k_conv_mfma<5, 1, 4, 50, 2, 60, 64>), dim3(Nc / 64), b256, 0, stream,
                     u_pad, wpk0, o0b, off0t);
  hipLaunchKernelGGL((k_deform<5, 1, 2, 2, 60, 9, 74, 64>), dim3(Nc * 24 / 256), b256, 0, stream,
                     u_pad, off0t, dwt0, d0b, (float*)nullptr, a0_pad);
  hipLaunchKernelGGL((k_conv_mfma<7, 3, 7, 98, 9, 74, 112>), dim3(Nc / 64), b256, 0, stream,
                     a0_pad, wpk1, o1b, off1t);
  hipLaunchKernelGGL((k_deform<7, 3, 9, 9, 74, 9, 74, 112>), dim3(Nc * 24 / 256), b256, 0, stream,
                     a0_pad, off1t, dwt1, d1b, a1, (unsigned short*)nullptr);
  hipLaunchKernelGGL((k_pw96<2, 60>), dim3(Nc / 64), b64x4, 0, stream, a1, c1w, c1b, A,
                     (unsigned short*)nullptr, 0);
  hipLaunchKernelGGL(k_combine, dim3(Nc / 64), b64x4, 0, stream,
                     x, u, A, yln, p2w, p2b, ls1, y2, out);
  hipLaunchKernelGGL(k_mlp1, dim3(Nc / 256), b256, 0, stream, y2, g2n, b2n, f1w, f1b, z4);
  hipLaunchKernelGGL(k_mlp_dw, dim3(Nc * 4 / 256), b256, 0, stream, z4, dww, dwb, z4b);
  hipLaunchKernelGGL(k_mlp2, dim3(Nc / 256), b256, 0, stream, z4b, f2w, f2b, ls2, out);
}

// Round 4
// 360.385 us; speedup vs baseline: 17.7796x; 1.0662x over previous
//
#include <hip/hip_runtime.h>
#include <math.h>

namespace {

constexpr int Bc = 4, Cc = 96, Hc = 56, Wc = 56;
constexpr int HWc = Hc * Wc;       // 3136
constexpr int Nc  = Bc * HWc;      // 12544
constexpr float EPSc = 1e-5f;

typedef __attribute__((ext_vector_type(8))) short bf16x8;
typedef __attribute__((ext_vector_type(4))) float f32x4;

__device__ __forceinline__ unsigned short f2bf(float f) {
  union { float f; unsigned u; } x; x.f = f;
  unsigned r = x.u + 0x7fffu + ((x.u >> 16) & 1u);
  return (unsigned short)(r >> 16);
}
__device__ __forceinline__ float bf2f(unsigned short u) {
  union { unsigned u; float f; } x; x.u = (unsigned)u << 16; return x.f;
}
__device__ __forceinline__ float gelu_exact(float x) {
  return 0.5f * x * (1.0f + erff(x * 0.7071067811865475f));
}

// ---------------- LayerNorm over channel dim (NCHW) ----------------
__global__ __launch_bounds__(256) void k_ln(const float* __restrict__ x,
                                            const float* __restrict__ g,
                                            const float* __restrict__ b,
                                            float* __restrict__ out) {
  int pos = blockIdx.x * 256 + threadIdx.x;
  int bb = pos / HWc, hw = pos % HWc;
  const float* xb = x + (size_t)bb * Cc * HWc + hw;
  float s = 0.f, s2 = 0.f;
  for (int c = 0; c < Cc; ++c) { float v = xb[c * HWc]; s += v; s2 += v * v; }
  float mu  = s * (1.f / Cc);
  float var = fmaxf(s2 * (1.f / Cc) - mu * mu, 0.f);
  float rs  = rsqrtf(var + EPSc);
  float* ob = out + (size_t)bb * Cc * HWc + hw;
  for (int c = 0; c < Cc; ++c) {
    float v = xb[c * HWc];
    ob[c * HWc] = (v - mu) * rs * g[c] + b[c];
  }
}

// ---------------- 1x1 conv 96->96; optional GELU; optional padded-NHWC-bf16 out ----------------
template <int PADP, int WP>
__global__ __launch_bounds__(256) void k_pw96(const float* __restrict__ src,
                                              const float* __restrict__ wq,
                                              const float* __restrict__ bq,
                                              float* __restrict__ dst,
                                              unsigned short* __restrict__ padOut,
                                              int do_gelu) {
  int spos = blockIdx.x * 64 + threadIdx.x;
  int og = threadIdx.y;                          // wave-uniform
  int bb = spos / HWc, hw = spos % HWc;
  const float* sb = src + (size_t)bb * Cc * HWc + hw;
  float acc[24];
#pragma unroll
  for (int o = 0; o < 24; ++o) acc[o] = 0.f;
  for (int c = 0; c < Cc; ++c) {
    float v = sb[c * HWc];
    const float* wr = wq + (og * 24) * Cc + c;
#pragma unroll
    for (int o = 0; o < 24; ++o) acc[o] += v * wr[o * Cc];
  }
  float* db_ = dst + (size_t)bb * Cc * HWc + hw;
  float res[24];
#pragma unroll
  for (int o = 0; o < 24; ++o) {
    int oc = og * 24 + o;
    float r = acc[o] + bq[oc];
    if (do_gelu) r = gelu_exact(r);
    res[o] = r;
    db_[oc * HWc] = r;
  }
  if (padOut) {
    int h = hw / Wc, w = hw % Wc;
    unsigned short tmp[24];
#pragma unroll
    for (int o = 0; o < 24; ++o) tmp[o] = f2bf(res[o]);
    unsigned short* tb = padOut + (((size_t)bb * (Hc + 2 * PADP) + h + PADP) * WP + w + PADP) * Cc + og * 24;
#pragma unroll
    for (int q = 0; q < 3; ++q)
      *reinterpret_cast<bf16x8*>(tb + q * 8) = *reinterpret_cast<const bf16x8*>(tmp + q * 8);
  }
}

// ---------------- weight pack: W[o][c][ky][kx] -> frag layout bf16 ----------------
template <int K_, int MTILES, int P>
__global__ __launch_bounds__(256) void k_pack_w(const float* __restrict__ wsrc,
                                                unsigned short* __restrict__ wpk) {
  constexpr int TOTAL = K_ * K_ * 3 * MTILES * 512;
  int idx = blockIdx.x * 256 + threadIdx.x;
  if (idx >= TOTAL) return;
  int j    = idx & 7;
  int lane = (idx >> 3) & 63;
  int t    = idx >> 9;             // step*MTILES + mt
  int mt   = t % MTILES;
  int step = t / MTILES;
  int o = mt * 16 + (lane & 15);
  int k = step * 32 + ((lane >> 4) & 3) * 8 + j;
  int p = k / Cc, c = k % Cc;
  float v = 0.f;
  if (o < P) v = wsrc[(((size_t)o * Cc + c) * K_ + p / K_) * K_ + (p % K_)];
  wpk[idx] = f2bf(v);
}

// ---------------- depthwise weight transpose [C][KK] -> [KK][C] ----------------
__global__ __launch_bounds__(256) void k_pack_dwt(const float* __restrict__ dwsrc,
                                                  float* __restrict__ dwt, int KK) {
  int idx = blockIdx.x * 256 + threadIdx.x;
  if (idx >= KK * Cc) return;
  int p = idx / Cc, c = idx % Cc;
  dwt[idx] = dwsrc[c * KK + p];
}

// ---------------- implicit-GEMM MFMA conv v2: wave = (32-pos n-tile, m-group) ----------------
// grid: (Nc/32/4, MGROUPS); block 256 = 4 waves.
template <int K_, int DIL_, int MTILES, int MT, int P, int PADP, int WP, int PSTR>
__global__ __launch_bounds__(256) void k_conv_mfma(const unsigned short* __restrict__ inp,
                                                   const unsigned short* __restrict__ wpk,
                                                   const float* __restrict__ bq,
                                                   float* __restrict__ dstT) {
  constexpr int KK = K_ * K_;
  constexpr int HP = Hc + 2 * PADP;
  int lane = threadIdx.x & 63;
  int wv = threadIdx.x >> 6;
  int ntile = blockIdx.x * 4 + wv;               // 32-position tile, wave-uniform
  int mg = blockIdx.y;                           // m-group
  int n0 = ntile * 32 + (lane & 15);
  int n1 = n0 + 16;
  int b0 = n0 / HWc, hw0 = n0 % HWc, h0 = hw0 / Wc, w0 = hw0 % Wc;
  int b1 = n1 / HWc, hw1 = n1 % HWc, h1 = hw1 / Wc, w1 = hw1 % Wc;
  int co = ((lane >> 4) & 3) * 8;
  const unsigned short* ib0 = inp + ((size_t)b0 * HP * WP + (size_t)h0 * WP + w0) * Cc + co;
  const unsigned short* ib1 = inp + ((size_t)b1 * HP * WP + (size_t)h1 * WP + w1) * Cc + co;
  int mtv[MT];
#pragma unroll
  for (int i = 0; i < MT; ++i) mtv[i] = min(mg * MT + i, MTILES - 1);
  f32x4 acc[MT][2];
#pragma unroll
  for (int i = 0; i < MT; ++i) {
    acc[i][0] = (f32x4){0.f, 0.f, 0.f, 0.f};
    acc[i][1] = (f32x4){0.f, 0.f, 0.f, 0.f};
  }
  for (int p = 0; p < KK; ++p) {
    size_t toff = (size_t)((p / K_) * DIL_ * WP + (p % K_) * DIL_) * Cc;
    const unsigned short* sp0 = ib0 + toff;
    const unsigned short* sp1 = ib1 + toff;
#pragma unroll
    for (int cc = 0; cc < 3; ++cc) {
      bf16x8 bf0 = *reinterpret_cast<const bf16x8*>(sp0 + cc * 32);
      bf16x8 bf1 = *reinterpret_cast<const bf16x8*>(sp1 + cc * 32);
      const unsigned short* wbase = wpk + ((size_t)(p * 3 + cc) * MTILES) * 512 + (size_t)lane * 8;
#pragma unroll
      for (int i = 0; i < MT; ++i) {
        bf16x8 af = *reinterpret_cast<const bf16x8*>(wbase + (size_t)mtv[i] * 512);
        acc[i][0] = __builtin_amdgcn_mfma_f32_16x16x32_bf16(af, bf0, acc[i][0], 0, 0, 0);
        acc[i][1] = __builtin_amdgcn_mfma_f32_16x16x32_bf16(af, bf1, acc[i][1], 0, 0, 0);
      }
    }
  }
  int orow = ((lane >> 4) & 3) * 4;
#pragma unroll
  for (int i = 0; i < MT; ++i) {
    int mt = mg * MT + i;
    if (mt >= MTILES) break;
#pragma unroll
    for (int nt = 0; nt < 2; ++nt) {
      float4 st;
#pragma unroll
      for (int j = 0; j < 4; ++j) {
        int o = mt * 16 + orow + j;
        float bias = (o < P) ? bq[o] : 0.f;
        ((float*)&st)[j] = acc[i][nt][j] + bias;
      }
      int n = ntile * 32 + nt * 16 + (lane & 15);
      *reinterpret_cast<float4*>(dstT + (size_t)n * PSTR + mt * 16 + orow) = st;
    }
  }
}

// ---------------- deformable depthwise sampling (bf16 padded NHWC src) ----------------
// offT: [pos][PSTR] transposed offsets; dwt: [KK][C]
template <int K_, int DIL_, int PAD_, int IPADP, int IWP, int OPADP, int OWP, int PSTR>
__global__ __launch_bounds__(256) void k_deform(const unsigned short* __restrict__ srcT,
                                                const float* __restrict__ offT,
                                                const float* __restrict__ dwt,
                                                const float* __restrict__ dbq,
                                                float* __restrict__ dst,
                                                unsigned short* __restrict__ dstPad) {
  constexpr int KK = K_ * K_;
  constexpr int KK4 = KK & ~3;
  constexpr int IHP = Hc + 2 * IPADP;
  int tid = blockIdx.x * 256 + threadIdx.x;      // N*24 threads
  int cg = tid % 24;
  int pos = tid / 24;
  int c = cg * 4;
  int bb = pos / HWc, hw = pos % HWc;
  int h = hw / Wc, w = hw % Wc;
  const unsigned short* sb = srcT + (size_t)bb * IHP * IWP * Cc + c;
  const float* ob = offT + (size_t)pos * PSTR;
  float ax = 0.f, ay = 0.f, az = 0.f, aw = 0.f;

  for (int pg = 0; pg < KK4; pg += 4) {
    float4 o01 = *reinterpret_cast<const float4*>(ob + 2 * pg);
    float4 o23 = *reinterpret_cast<const float4*>(ob + 2 * pg + 4);
    float oyv[4] = {o01.x, o01.z, o23.x, o23.z};
    float oxv[4] = {o01.y, o01.w, o23.y, o23.w};
    uint2 v[4][4];
    float wt[4][4];
#pragma unroll
    for (int i = 0; i < 4; ++i) {
      int p = pg + i;
      float py = (float)(h + (p / K_) * DIL_ - PAD_) + oyv[i];
      float px = (float)(w + (p % K_) * DIL_ - PAD_) + oxv[i];
      float y0f = floorf(py), x0f = floorf(px);
      float wy = py - y0f, wx = px - x0f;
      int y0 = (int)y0f, x0 = (int)x0f;
#pragma unroll
      for (int dy = 0; dy < 2; ++dy) {
        int yi = y0 + dy;
        bool yv = (unsigned)yi < (unsigned)Hc;
        int yc = min(max(yi, 0), Hc - 1);
        float wyv = dy ? wy : 1.f - wy;
#pragma unroll
        for (int dx = 0; dx < 2; ++dx) {
          int xi = x0 + dx;
          bool xv = (unsigned)xi < (unsigned)Wc;
          int xc = min(max(xi, 0), Wc - 1);
          wt[i][dy * 2 + dx] = (yv && xv) ? wyv * (dx ? wx : 1.f - wx) : 0.f;
          v[i][dy * 2 + dx] = *reinterpret_cast<const uint2*>(
              sb + ((size_t)(yc + IPADP) * IWP + (xc + IPADP)) * Cc);
        }
      }
    }
#pragma unroll
    for (int i = 0; i < 4; ++i) {
      int p = pg + i;
      float4 d = *reinterpret_cast<const float4*>(dwt + (size_t)p * Cc + c);
      float sx = 0.f, sy = 0.f, sz = 0.f, sw = 0.f;
#pragma unroll
      for (int q = 0; q < 4; ++q) {
        float wq_ = wt[i][q];
        sx += wq_ * bf2f((unsigned short)(v[i][q].x & 0xffffu));
        sy += wq_ * bf2f((unsigned short)(v[i][q].x >> 16));
        sz += wq_ * bf2f((unsigned short)(v[i][q].y & 0xffffu));
        sw += wq_ * bf2f((unsigned short)(v[i][q].y >> 16));
      }
      ax += sx * d.x; ay += sy * d.y; az += sz * d.z; aw += sw * d.w;
    }
  }
  // tail tap (KK % 4 == 1 for K=5,7)
  {
    int p = KK - 1;
    float oy = ob[2 * p], ox = ob[2 * p + 1];
    float py = (float)(h + (p / K_) * DIL_ - PAD_) + oy;
    float px = (float)(w + (p % K_) * DIL_ - PAD_) + ox;
    float y0f = floorf(py), x0f = floorf(px);
    float wy = py - y0f, wx = px - x0f;
    int y0 = (int)y0f, x0 = (int)x0f;
    uint2 v[4]; float wt[4];
#pragma unroll
    for (int dy = 0; dy < 2; ++dy) {
      int yi = y0 + dy;
      bool yv = (unsigned)yi < (unsigned)Hc;
      int yc = min(max(yi, 0), Hc - 1);
      float wyv = dy ? wy : 1.f - wy;
#pragma unroll
      for (int dx = 0; dx < 2; ++dx) {
        int xi = x0 + dx;
        bool xv = (unsigned)xi < (unsigned)Wc;
        int xc = min(max(xi, 0), Wc - 1);
        wt[dy * 2 + dx] = (yv && xv) ? wyv * (dx ? wx : 1.f - wx) : 0.f;
        v[dy * 2 + dx] = *reinterpret_cast<const uint2*>(
            sb + ((size_t)(yc + IPADP) * IWP + (xc + IPADP)) * Cc);
      }
    }
    float4 d = *reinterpret_cast<const float4*>(dwt + (size_t)p * Cc + c);
    float sx = 0.f, sy = 0.f, sz = 0.f, sw = 0.f;
#pragma unroll
    for (int q = 0; q < 4; ++q) {
      sx += wt[q] * bf2f((unsigned short)(v[q].x & 0xffffu));
      sy += wt[q] * bf2f((unsigned short)(v[q].x >> 16));
      sz += wt[q] * bf2f((unsigned short)(v[q].y & 0xffffu));
      sw += wt[q] * bf2f((unsigned short)(v[q].y >> 16));
    }
    ax += sx * d.x; ay += sy * d.y; az += sz * d.z; aw += sw * d.w;
  }

  ax += dbq[c]; ay += dbq[c + 1]; az += dbq[c + 2]; aw += dbq[c + 3];
  if (dst) {
    float* d = dst + (size_t)bb * Cc * HWc + hw;
    d[(c + 0) * HWc] = ax; d[(c + 1) * HWc] = ay;
    d[(c + 2) * HWc] = az; d[(c + 3) * HWc] = aw;
  }
  if (dstPad) {
    unsigned short t4[4] = {f2bf(ax), f2bf(ay), f2bf(az), f2bf(aw)};
    unsigned short* tb = dstPad + (((size_t)bb * (Hc + 2 * OPADP) + h + OPADP) * OWP + w + OPADP) * Cc + c;
    *reinterpret_cast<uint2*>(tb) = *reinterpret_cast<const uint2*>(t4);
  }
}

// ---------------- gated projection + shortcut + ls1 + residual ----------------
__global__ __launch_bounds__(256) void k_combine(const float* __restrict__ x,
                                                 const float* __restrict__ u,
                                                 const float* __restrict__ a,
                                                 const float* __restrict__ yln,
                                                 const float* __restrict__ wq,
                                                 const float* __restrict__ bq,
                                                 const float* __restrict__ ls1q,
                                                 float* __restrict__ y2,
                                                 float* __restrict__ xo) {
  int spos = blockIdx.x * 64 + threadIdx.x;
  int og = threadIdx.y;
  int bb = spos / HWc, hw = spos % HWc;
  size_t base = (size_t)bb * Cc * HWc + hw;
  float acc[24];
#pragma unroll
  for (int o = 0; o < 24; ++o) acc[o] = 0.f;
  for (int c = 0; c < Cc; ++c) {
    float v = u[base + (size_t)c * HWc] * a[base + (size_t)c * HWc];
    const float* wr = wq + (og * 24) * Cc + c;
#pragma unroll
    for (int o = 0; o < 24; ++o) acc[o] += v * wr[o * Cc];
  }
#pragma unroll
  for (int o = 0; o < 24; ++o) {
    int oc = og * 24 + o;
    float t = acc[o] + bq[oc] + yln[base + (size_t)oc * HWc];
    float yv = ls1q[oc] * t;
    y2[base + (size_t)oc * HWc] = yv;
    xo[base + (size_t)oc * HWc] = x[base + (size_t)oc * HWc] + yv;
  }
}

// ---------------- MLP: LN2 + f1 (96->4) ----------------
__global__ __launch_bounds__(256) void k_mlp1(const float* __restrict__ y2,
                                              const float* __restrict__ g,
                                              const float* __restrict__ b,
                                              const float* __restrict__ f1wq,
                                              const float* __restrict__ f1bq,
                                              float* __restrict__ z4) {
  int pos = blockIdx.x * 256 + threadIdx.x;
  int bb = pos / HWc, hw = pos % HWc;
  const float* yb = y2 + (size_t)bb * Cc * HWc + hw;
  float s = 0.f, s2 = 0.f;
  for (int c = 0; c < Cc; ++c) { float v = yb[c * HWc]; s += v; s2 += v * v; }
  float mu  = s * (1.f / Cc);
  float var = fmaxf(s2 * (1.f / Cc) - mu * mu, 0.f);
  float rs  = rsqrtf(var + EPSc);
  float a0 = 0.f, a1 = 0.f, a2 = 0.f, a3 = 0.f;
  for (int c = 0; c < Cc; ++c) {
    float t = (yb[c * HWc] - mu) * rs * g[c] + b[c];
    a0 += t * f1wq[0 * Cc + c];
    a1 += t * f1wq[1 * Cc + c];
    a2 += t * f1wq[2 * Cc + c];
    a3 += t * f1wq[3 * Cc + c];
  }
  float* zb = z4 + (size_t)bb * 4 * HWc + hw;
  zb[0 * HWc] = a0 + f1bq[0];
  zb[1 * HWc] = a1 + f1bq[1];
  zb[2 * HWc] = a2 + f1bq[2];
  zb[3 * HWc] = a3 + f1bq[3];
}

// ---------------- MLP: depthwise 3x3 (4 ch) + GELU ----------------
__global__ __launch_bounds__(256) void k_mlp_dw(const float* __restrict__ z4,
                                                const float* __restrict__ dwwq,
                                                const float* __restrict__ dwbq,
                                                float* __restrict__ z4b) {
  int tid = blockIdx.x * 256 + threadIdx.x;
  int hw = tid % HWc;
  int bj = tid / HWc;
  int j = bj % 4;
  int h = hw / Wc, w = hw % Wc;
  const float* zb = z4 + (size_t)bj * HWc;
  float s = 0.f;
#pragma unroll
  for (int ky = 0; ky < 3; ++ky) {
    int y = h + ky - 1;
    if ((unsigned)y >= (unsigned)Hc) continue;
#pragma unroll
    for (int kx = 0; kx < 3; ++kx) {
      int x = w + kx - 1;
      if ((unsigned)x >= (unsigned)Wc) continue;
      s += zb[y * Wc + x] * dwwq[j * 9 + ky * 3 + kx];
    }
  }
  z4b[tid] = gelu_exact(s + dwbq[j]);
}

// ---------------- MLP: f2 (4->96) + ls2 + residual add into out ----------------
__global__ __launch_bounds__(256) void k_mlp2(const float* __restrict__ z4b,
                                              const float* __restrict__ f2wq,
                                              const float* __restrict__ f2bq,
                                              const float* __restrict__ ls2q,
                                              float* __restrict__ out) {
  int pos = blockIdx.x * 256 + threadIdx.x;
  int bb = pos / HWc, hw = pos % HWc;
  const float* zb = z4b + (size_t)bb * 4 * HWc + hw;
  float z0 = zb[0 * HWc], z1 = zb[1 * HWc], z2 = zb[2 * HWc], z3 = zb[3 * HWc];
  float* ob = out + (size_t)bb * Cc * HWc + hw;
  for (int o = 0; o < Cc; ++o) {
    float s = f2bq[o] + z0 * f2wq[o * 4 + 0] + z1 * f2wq[o * 4 + 1]
                      + z2 * f2wq[o * 4 + 2] + z3 * f2wq[o * 4 + 3];
    ob[o * HWc] += ls2q[o] * s;
  }
}

}  // namespace

extern "C" void kernel_launch(void* const* d_in, const int* in_sizes, int n_in,
                              void* d_out, int out_size, void* d_ws, size_t ws_size,
                              hipStream_t stream) {
  (void)in_sizes; (void)n_in; (void)out_size; (void)ws_size;
  const float* x   = (const float*)d_in[0];
  const float* g1n = (const float*)d_in[1];
  const float* b1n = (const float*)d_in[2];
  const float* p1w = (const float*)d_in[3];
  const float* p1b = (const float*)d_in[4];
  const float* o0w = (const float*)d_in[5];
  const float* o0b = (const float*)d_in[6];
  const float* d0w = (const float*)d_in[7];
  const float* d0b = (const float*)d_in[8];
  const float* o1w = (const float*)d_in[9];
  const float* o1b = (const float*)d_in[10];
  const float* d1w = (const float*)d_in[11];
  const float* d1b = (const float*)d_in[12];
  const float* c1w = (const float*)d_in[13];
  const float* c1b = (const float*)d_in[14];
  const float* p2w = (const float*)d_in[15];
  const float* p2b = (const float*)d_in[16];
  const float* ls1 = (const float*)d_in[17];
  const float* g2n = (const float*)d_in[18];
  const float* b2n = (const float*)d_in[19];
  const float* f1w = (const float*)d_in[20];
  const float* f1b = (const float*)d_in[21];
  const float* dww = (const float*)d_in[22];
  const float* dwb = (const float*)d_in[23];
  const float* f2w = (const float*)d_in[24];
  const float* f2b = (const float*)d_in[25];
  const float* ls2 = (const float*)d_in[26];
  float* out = (float*)d_out;
  float* ws  = (float*)d_ws;

  const size_t NC = (size_t)Nc * Cc;
  float* yln   = ws;                                  size_t o_ = NC;
  float* u     = ws + o_;                             o_ += NC;
  float* A     = ws + o_;                             o_ += NC;
  float* y2    = ws + o_;                             o_ += NC;
  float* a1    = ws + o_;                             o_ += NC;
  float* off0t = ws + o_;                             o_ += (size_t)Nc * 64;
  float* off1t = ws + o_;                             o_ += (size_t)Nc * 112;
  float* z4    = ws + o_;                             o_ += (size_t)Bc * 4 * HWc;
  float* z4b   = ws + o_;                             o_ += (size_t)Bc * 4 * HWc;
  float* dwt0  = ws + o_;                             o_ += 25 * Cc;
  float* dwt1  = ws + o_;                             o_ += 49 * Cc;
  unsigned short* u_pad  = (unsigned short*)(ws + o_); o_ += (size_t)Bc * 60 * 60 * Cc / 2;
  unsigned short* a0_pad = (unsigned short*)(ws + o_); o_ += (size_t)Bc * 74 * 74 * Cc / 2;
  unsigned short* wpk0   = (unsigned short*)(ws + o_); o_ += (size_t)25 * 3 * 4 * 512 / 2;
  unsigned short* wpk1   = (unsigned short*)(ws + o_); o_ += (size_t)49 * 3 * 7 * 512 / 2;

  dim3 b256(256, 1, 1), b64x4(64, 4, 1);

  hipMemsetAsync(u_pad, 0, (size_t)Bc * 60 * 60 * Cc * sizeof(unsigned short), stream);
  hipMemsetAsync(a0_pad, 0, (size_t)Bc * 74 * 74 * Cc * sizeof(unsigned short), stream);
  hipLaunchKernelGGL((k_pack_w<5, 4, 50>), dim3((25 * 3 * 4 * 512 + 255) / 256), b256, 0, stream, o0w, wpk0);
  hipLaunchKernelGGL((k_pack_w<7, 7, 98>), dim3((49 * 3 * 7 * 512 + 255) / 256), b256, 0, stream, o1w, wpk1);
  hipLaunchKernelGGL(k_pack_dwt, dim3((25 * Cc + 255) / 256), b256, 0, stream, d0w, dwt0, 25);
  hipLaunchKernelGGL(k_pack_dwt, dim3((49 * Cc + 255) / 256), b256, 0, stream, d1w, dwt1, 49);

  hipLaunchKernelGGL(k_ln, dim3(Nc / 256), b256, 0, stream, x, g1n, b1n, yln);
  hipLaunchKernelGGL((k_pw96<2, 60>), dim3(Nc / 64), b64x4, 0, stream, yln, p1w, p1b, u, u_pad, 1);
  // conv5: MTILES=4, MT=1, 4 m-groups ; conv7: MTILES=7, MT=2, 4 m-groups
  hipLaunchKernelGGL((k_conv_mfma<5, 1, 4, 1, 50, 2, 60, 64>), dim3(Nc / 128, 4), b256, 0, stream,
                     u_pad, wpk0, o0b, off0t);
  hipLaunchKernelGGL((k_deform<5, 1, 2, 2, 60, 9, 74, 64>), dim3(Nc * 24 / 256), b256, 0, stream,
                     u_pad, off0t, dwt0, d0b, (float*)nullptr, a0_pad);
  hipLaunchKernelGGL((k_conv_mfma<7, 3, 7, 2, 98, 9, 74, 112>), dim3(Nc / 128, 4), b256, 0, stream,
                     a0_pad, wpk1, o1b, off1t);
  hipLaunchKernelGGL((k_deform<7, 3, 9, 9, 74, 9, 74, 112>), dim3(Nc * 24 / 256), b256, 0, stream,
                     a0_pad, off1t, dwt1, d1b, a1, (unsigned short*)nullptr);
  hipLaunchKernelGGL((k_pw96<2, 60>), dim3(Nc / 64), b64x4, 0, stream, a1, c1w, c1b, A,
                     (unsigned short*)nullptr, 0);
  hipLaunchKernelGGL(k_combine, dim3(Nc / 64), b64x4, 0, stream,
                     x, u, A, yln, p2w, p2b, ls1, y2, out);
  hipLaunchKernelGGL(k_mlp1, dim3(Nc / 256), b256, 0, stream, y2, g2n, b2n, f1w, f1b, z4);
  hipLaunchKernelGGL(k_mlp_dw, dim3(Nc * 4 / 256), b256, 0, stream, z4, dww, dwb, z4b);
  hipLaunchKernelGGL(k_mlp2, dim3(Nc / 256), b256, 0, stream, z4b, f2w, f2b, ls2, out);
}

// Round 5
// 339.310 us; speedup vs baseline: 18.8838x; 1.0621x over previous
//
#include <hip/hip_runtime.h>
#include <math.h>

namespace {

constexpr int Bc = 4, Cc = 96, Hc = 56, Wc = 56;
constexpr int HWc = Hc * Wc;       // 3136
constexpr int Nc  = Bc * HWc;      // 12544
constexpr float EPSc = 1e-5f;

typedef __attribute__((ext_vector_type(8))) short bf16x8;
typedef __attribute__((ext_vector_type(4))) float f32x4;

__device__ __forceinline__ unsigned short f2bf(float f) {
  union { float f; unsigned u; } x; x.f = f;
  unsigned r = x.u + 0x7fffu + ((x.u >> 16) & 1u);
  return (unsigned short)(r >> 16);
}
__device__ __forceinline__ float bf2f(unsigned short u) {
  union { unsigned u; float f; } x; x.u = (unsigned)u << 16; return x.f;
}
__device__ __forceinline__ float gelu_exact(float x) {
  return 0.5f * x * (1.0f + erff(x * 0.7071067811865475f));
}

// ---------------- LayerNorm over channel dim (NCHW) ----------------
__global__ __launch_bounds__(256) void k_ln(const float* __restrict__ x,
                                            const float* __restrict__ g,
                                            const float* __restrict__ b,
                                            float* __restrict__ out) {
  int pos = blockIdx.x * 256 + threadIdx.x;
  int bb = pos / HWc, hw = pos % HWc;
  const float* xb = x + (size_t)bb * Cc * HWc + hw;
  float s = 0.f, s2 = 0.f;
  for (int c = 0; c < Cc; ++c) { float v = xb[c * HWc]; s += v; s2 += v * v; }
  float mu  = s * (1.f / Cc);
  float var = fmaxf(s2 * (1.f / Cc) - mu * mu, 0.f);
  float rs  = rsqrtf(var + EPSc);
  float* ob = out + (size_t)bb * Cc * HWc + hw;
  for (int c = 0; c < Cc; ++c) {
    float v = xb[c * HWc];
    ob[c * HWc] = (v - mu) * rs * g[c] + b[c];
  }
}

// ---------------- 1x1 conv 96->96; optional GELU; optional padded-NHWC-bf16 out ----------------
template <int PADP, int WP>
__global__ __launch_bounds__(256) void k_pw96(const float* __restrict__ src,
                                              const float* __restrict__ wq,
                                              const float* __restrict__ bq,
                                              float* __restrict__ dst,
                                              unsigned short* __restrict__ padOut,
                                              int do_gelu) {
  int spos = blockIdx.x * 64 + threadIdx.x;
  int og = threadIdx.y;                          // wave-uniform
  int bb = spos / HWc, hw = spos % HWc;
  const float* sb = src + (size_t)bb * Cc * HWc + hw;
  float acc[24];
#pragma unroll
  for (int o = 0; o < 24; ++o) acc[o] = 0.f;
  for (int c = 0; c < Cc; ++c) {
    float v = sb[c * HWc];
    const float* wr = wq + (og * 24) * Cc + c;
#pragma unroll
    for (int o = 0; o < 24; ++o) acc[o] += v * wr[o * Cc];
  }
  float* db_ = dst + (size_t)bb * Cc * HWc + hw;
  float res[24];
#pragma unroll
  for (int o = 0; o < 24; ++o) {
    int oc = og * 24 + o;
    float r = acc[o] + bq[oc];
    if (do_gelu) r = gelu_exact(r);
    res[o] = r;
    db_[oc * HWc] = r;
  }
  if (padOut) {
    int h = hw / Wc, w = hw % Wc;
    unsigned short tmp[24];
#pragma unroll
    for (int o = 0; o < 24; ++o) tmp[o] = f2bf(res[o]);
    unsigned short* tb = padOut + (((size_t)bb * (Hc + 2 * PADP) + h + PADP) * WP + w + PADP) * Cc + og * 24;
#pragma unroll
    for (int q = 0; q < 3; ++q)
      *reinterpret_cast<bf16x8*>(tb + q * 8) = *reinterpret_cast<const bf16x8*>(tmp + q * 8);
  }
}

// ---------------- weight pack: W[o][c][ky][kx] -> frag layout bf16 ----------------
template <int K_, int MTILES, int P>
__global__ __launch_bounds__(256) void k_pack_w(const float* __restrict__ wsrc,
                                                unsigned short* __restrict__ wpk) {
  constexpr int TOTAL = K_ * K_ * 3 * MTILES * 512;
  int idx = blockIdx.x * 256 + threadIdx.x;
  if (idx >= TOTAL) return;
  int j    = idx & 7;
  int lane = (idx >> 3) & 63;
  int t    = idx >> 9;             // (p*3+cc)*MTILES + mt
  int mt   = t % MTILES;
  int step = t / MTILES;
  int o = mt * 16 + (lane & 15);
  int k = step * 32 + ((lane >> 4) & 3) * 8 + j;
  int p = k / Cc, c = k % Cc;
  float v = 0.f;
  if (o < P) v = wsrc[(((size_t)o * Cc + c) * K_ + p / K_) * K_ + (p % K_)];
  wpk[idx] = f2bf(v);
}

// ---------------- depthwise weight transpose [C][KK] -> [KK][C] ----------------
__global__ __launch_bounds__(256) void k_pack_dwt(const float* __restrict__ dwsrc,
                                                  float* __restrict__ dwt, int KK) {
  int idx = blockIdx.x * 256 + threadIdx.x;
  if (idx >= KK * Cc) return;
  int p = idx / Cc, c = idx % Cc;
  dwt[idx] = dwsrc[c * KK + p];
}

// ---------------- implicit-GEMM MFMA conv v3 ----------------
// block 256 = 4 waves, all on ONE 16-position n-tile, wave = m-chunk (L1 B-share).
// Register double-buffer across taps. Grid: Nc/16 blocks, XCD-swizzled.
template <int K_, int DIL_, int MTILES, int MT, int P, int PADP, int WP, int PSTR>
__global__ __launch_bounds__(256) void k_conv_mfma(const unsigned short* __restrict__ inp,
                                                   const unsigned short* __restrict__ wpk,
                                                   const float* __restrict__ bq,
                                                   float* __restrict__ dstT) {
  constexpr int KK = K_ * K_;
  constexpr int HP = Hc + 2 * PADP;
  constexpr int NBLK = Nc / 16;                  // 784
  int lane = threadIdx.x & 63;
  int wv = threadIdx.x >> 6;
  int bid = blockIdx.x;
  int ntile = (bid & 7) * (NBLK / 8) + (bid >> 3);   // XCD swizzle (784 % 8 == 0)
  int n = ntile * 16 + (lane & 15);
  int b = n / HWc, hw = n % HWc;
  int h = hw / Wc, w = hw % Wc;
  int co = ((lane >> 4) & 3) * 8;
  const unsigned short* ib = inp + ((size_t)b * HP * WP + (size_t)h * WP + w) * Cc + co;
  const unsigned short* wl = wpk + (size_t)lane * 8;
  int mt0 = wv * MT;
  int mtc[MT];
#pragma unroll
  for (int i = 0; i < MT; ++i) mtc[i] = min(mt0 + i, MTILES - 1);

  f32x4 acc[MT];
#pragma unroll
  for (int i = 0; i < MT; ++i) acc[i] = (f32x4){0.f, 0.f, 0.f, 0.f};

  bf16x8 Bb[3], Aa[MT][3];
  // prologue: load tap 0
  {
    const unsigned short* sp = ib;               // tap 0 offset = 0? no: tap 0 has its own offset
  }
  {
    size_t t0 = 0;  // p=0: (0/K_)*DIL_*WP + (0%K_)*DIL_ = 0
    const unsigned short* sp = ib + t0 * Cc;
#pragma unroll
    for (int cc = 0; cc < 3; ++cc) {
      Bb[cc] = *reinterpret_cast<const bf16x8*>(sp + cc * 32);
#pragma unroll
      for (int i = 0; i < MT; ++i)
        Aa[i][cc] = *reinterpret_cast<const bf16x8*>(wl + ((size_t)(0 * 3 + cc) * MTILES + mtc[i]) * 512);
    }
  }

#pragma unroll 2
  for (int p = 0; p < KK; ++p) {
    int pn = (p + 1 < KK) ? p + 1 : p;
    size_t toff = (size_t)((pn / K_) * DIL_ * WP + (pn % K_) * DIL_) * Cc;
    const unsigned short* sp = ib + toff;
    bf16x8 Bn[3], An[MT][3];
#pragma unroll
    for (int cc = 0; cc < 3; ++cc) {
      Bn[cc] = *reinterpret_cast<const bf16x8*>(sp + cc * 32);
#pragma unroll
      for (int i = 0; i < MT; ++i)
        An[i][cc] = *reinterpret_cast<const bf16x8*>(wl + ((size_t)(pn * 3 + cc) * MTILES + mtc[i]) * 512);
    }
#pragma unroll
    for (int cc = 0; cc < 3; ++cc)
#pragma unroll
      for (int i = 0; i < MT; ++i)
        acc[i] = __builtin_amdgcn_mfma_f32_16x16x32_bf16(Aa[i][cc], Bb[cc], acc[i], 0, 0, 0);
#pragma unroll
    for (int cc = 0; cc < 3; ++cc) {
      Bb[cc] = Bn[cc];
#pragma unroll
      for (int i = 0; i < MT; ++i) Aa[i][cc] = An[i][cc];
    }
  }

  int orow = ((lane >> 4) & 3) * 4;
#pragma unroll
  for (int i = 0; i < MT; ++i) {
    int mt = mt0 + i;
    if (mt >= MTILES) break;
    float4 st;
#pragma unroll
    for (int j = 0; j < 4; ++j) {
      int o = mt * 16 + orow + j;
      float bias = (o < P) ? bq[o] : 0.f;
      ((float*)&st)[j] = acc[i][j] + bias;
    }
    *reinterpret_cast<float4*>(dstT + (size_t)n * PSTR + mt * 16 + orow) = st;
  }
}

// ---------------- deformable depthwise sampling (bf16 padded NHWC src) ----------------
// offT: [pos][PSTR] transposed offsets; dwt: [KK][C]
template <int K_, int DIL_, int PAD_, int IPADP, int IWP, int OPADP, int OWP, int PSTR>
__global__ __launch_bounds__(256) void k_deform(const unsigned short* __restrict__ srcT,
                                                const float* __restrict__ offT,
                                                const float* __restrict__ dwt,
                                                const float* __restrict__ dbq,
                                                float* __restrict__ dst,
                                                unsigned short* __restrict__ dstPad) {
  constexpr int KK = K_ * K_;
  constexpr int KK4 = KK & ~3;
  constexpr int IHP = Hc + 2 * IPADP;
  int tid = blockIdx.x * 256 + threadIdx.x;      // N*24 threads
  int cg = tid % 24;
  int pos = tid / 24;
  int c = cg * 4;
  int bb = pos / HWc, hw = pos % HWc;
  int h = hw / Wc, w = hw % Wc;
  const unsigned short* sb = srcT + (size_t)bb * IHP * IWP * Cc + c;
  const float* ob = offT + (size_t)pos * PSTR;
  float ax = 0.f, ay = 0.f, az = 0.f, aw = 0.f;

  for (int pg = 0; pg < KK4; pg += 4) {
    float4 o01 = *reinterpret_cast<const float4*>(ob + 2 * pg);
    float4 o23 = *reinterpret_cast<const float4*>(ob + 2 * pg + 4);
    float oyv[4] = {o01.x, o01.z, o23.x, o23.z};
    float oxv[4] = {o01.y, o01.w, o23.y, o23.w};
    uint2 v[4][4];
    float wt[4][4];
#pragma unroll
    for (int i = 0; i < 4; ++i) {
      int p = pg + i;
      float py = (float)(h + (p / K_) * DIL_ - PAD_) + oyv[i];
      float px = (float)(w + (p % K_) * DIL_ - PAD_) + oxv[i];
      float y0f = floorf(py), x0f = floorf(px);
      float wy = py - y0f, wx = px - x0f;
      int y0 = (int)y0f, x0 = (int)x0f;
#pragma unroll
      for (int dy = 0; dy < 2; ++dy) {
        int yi = y0 + dy;
        bool yv = (unsigned)yi < (unsigned)Hc;
        int yc = min(max(yi, 0), Hc - 1);
        float wyv = dy ? wy : 1.f - wy;
#pragma unroll
        for (int dx = 0; dx < 2; ++dx) {
          int xi = x0 + dx;
          bool xv = (unsigned)xi < (unsigned)Wc;
          int xc = min(max(xi, 0), Wc - 1);
          wt[i][dy * 2 + dx] = (yv && xv) ? wyv * (dx ? wx : 1.f - wx) : 0.f;
          v[i][dy * 2 + dx] = *reinterpret_cast<const uint2*>(
              sb + ((size_t)(yc + IPADP) * IWP + (xc + IPADP)) * Cc);
        }
      }
    }
#pragma unroll
    for (int i = 0; i < 4; ++i) {
      int p = pg + i;
      float4 d = *reinterpret_cast<const float4*>(dwt + (size_t)p * Cc + c);
      float sx = 0.f, sy = 0.f, sz = 0.f, sw = 0.f;
#pragma unroll
      for (int q = 0; q < 4; ++q) {
        float wq_ = wt[i][q];
        sx += wq_ * bf2f((unsigned short)(v[i][q].x & 0xffffu));
        sy += wq_ * bf2f((unsigned short)(v[i][q].x >> 16));
        sz += wq_ * bf2f((unsigned short)(v[i][q].y & 0xffffu));
        sw += wq_ * bf2f((unsigned short)(v[i][q].y >> 16));
      }
      ax += sx * d.x; ay += sy * d.y; az += sz * d.z; aw += sw * d.w;
    }
  }
  // tail tap (KK % 4 == 1 for K=5,7)
  {
    int p = KK - 1;
    float oy = ob[2 * p], ox = ob[2 * p + 1];
    float py = (float)(h + (p / K_) * DIL_ - PAD_) + oy;
    float px = (float)(w + (p % K_) * DIL_ - PAD_) + ox;
    float y0f = floorf(py), x0f = floorf(px);
    float wy = py - y0f, wx = px - x0f;
    int y0 = (int)y0f, x0 = (int)x0f;
    uint2 v[4]; float wt[4];
#pragma unroll
    for (int dy = 0; dy < 2; ++dy) {
      int yi = y0 + dy;
      bool yv = (unsigned)yi < (unsigned)Hc;
      int yc = min(max(yi, 0), Hc - 1);
      float wyv = dy ? wy : 1.f - wy;
#pragma unroll
      for (int dx = 0; dx < 2; ++dx) {
        int xi = x0 + dx;
        bool xv = (unsigned)xi < (unsigned)Wc;
        int xc = min(max(xi, 0), Wc - 1);
        wt[dy * 2 + dx] = (yv && xv) ? wyv * (dx ? wx : 1.f - wx) : 0.f;
        v[dy * 2 + dx] = *reinterpret_cast<const uint2*>(
            sb + ((size_t)(yc + IPADP) * IWP + (xc + IPADP)) * Cc);
      }
    }
    float4 d = *reinterpret_cast<const float4*>(dwt + (size_t)p * Cc + c);
    float sx = 0.f, sy = 0.f, sz = 0.f, sw = 0.f;
#pragma unroll
    for (int q = 0; q < 4; ++q) {
      sx += wt[q] * bf2f((unsigned short)(v[q].x & 0xffffu));
      sy += wt[q] * bf2f((unsigned short)(v[q].x >> 16));
      sz += wt[q] * bf2f((unsigned short)(v[q].y & 0xffffu));
      sw += wt[q] * bf2f((unsigned short)(v[q].y >> 16));
    }
    ax += sx * d.x; ay += sy * d.y; az += sz * d.z; aw += sw * d.w;
  }

  ax += dbq[c]; ay += dbq[c + 1]; az += dbq[c + 2]; aw += dbq[c + 3];
  if (dst) {
    float* d = dst + (size_t)bb * Cc * HWc + hw;
    d[(c + 0) * HWc] = ax; d[(c + 1) * HWc] = ay;
    d[(c + 2) * HWc] = az; d[(c + 3) * HWc] = aw;
  }
  if (dstPad) {
    unsigned short t4[4] = {f2bf(ax), f2bf(ay), f2bf(az), f2bf(aw)};
    unsigned short* tb = dstPad + (((size_t)bb * (Hc + 2 * OPADP) + h + OPADP) * OWP + w + OPADP) * Cc + c;
    *reinterpret_cast<uint2*>(tb) = *reinterpret_cast<const uint2*>(t4);
  }
}

// ---------------- gated projection + shortcut + ls1 + residual ----------------
__global__ __launch_bounds__(256) void k_combine(const float* __restrict__ x,
                                                 const float* __restrict__ u,
                                                 const float* __restrict__ a,
                                                 const float* __restrict__ yln,
                                                 const float* __restrict__ wq,
                                                 const float* __restrict__ bq,
                                                 const float* __restrict__ ls1q,
                                                 float* __restrict__ y2,
                                                 float* __restrict__ xo) {
  int spos = blockIdx.x * 64 + threadIdx.x;
  int og = threadIdx.y;
  int bb = spos / HWc, hw = spos % HWc;
  size_t base = (size_t)bb * Cc * HWc + hw;
  float acc[24];
#pragma unroll
  for (int o = 0; o < 24; ++o) acc[o] = 0.f;
  for (int c = 0; c < Cc; ++c) {
    float v = u[base + (size_t)c * HWc] * a[base + (size_t)c * HWc];
    const float* wr = wq + (og * 24) * Cc + c;
#pragma unroll
    for (int o = 0; o < 24; ++o) acc[o] += v * wr[o * Cc];
  }
#pragma unroll
  for (int o = 0; o < 24; ++o) {
    int oc = og * 24 + o;
    float t = acc[o] + bq[oc] + yln[base + (size_t)oc * HWc];
    float yv = ls1q[oc] * t;
    y2[base + (size_t)oc * HWc] = yv;
    xo[base + (size_t)oc * HWc] = x[base + (size_t)oc * HWc] + yv;
  }
}

// ---------------- MLP: LN2 + f1 (96->4) ----------------
__global__ __launch_bounds__(256) void k_mlp1(const float* __restrict__ y2,
                                              const float* __restrict__ g,
                                              const float* __restrict__ b,
                                              const float* __restrict__ f1wq,
                                              const float* __restrict__ f1bq,
                                              float* __restrict__ z4) {
  int pos = blockIdx.x * 256 + threadIdx.x;
  int bb = pos / HWc, hw = pos % HWc;
  const float* yb = y2 + (size_t)bb * Cc * HWc + hw;
  float s = 0.f, s2 = 0.f;
  for (int c = 0; c < Cc; ++c) { float v = yb[c * HWc]; s += v; s2 += v * v; }
  float mu  = s * (1.f / Cc);
  float var = fmaxf(s2 * (1.f / Cc) - mu * mu, 0.f);
  float rs  = rsqrtf(var + EPSc);
  float a0 = 0.f, a1 = 0.f, a2 = 0.f, a3 = 0.f;
  for (int c = 0; c < Cc; ++c) {
    float t = (yb[c * HWc] - mu) * rs * g[c] + b[c];
    a0 += t * f1wq[0 * Cc + c];
    a1 += t * f1wq[1 * Cc + c];
    a2 += t * f1wq[2 * Cc + c];
    a3 += t * f1wq[3 * Cc + c];
  }
  float* zb = z4 + (size_t)bb * 4 * HWc + hw;
  zb[0 * HWc] = a0 + f1bq[0];
  zb[1 * HWc] = a1 + f1bq[1];
  zb[2 * HWc] = a2 + f1bq[2];
  zb[3 * HWc] = a3 + f1bq[3];
}

// ---------------- MLP: depthwise 3x3 (4 ch) + GELU ----------------
__global__ __launch_bounds__(256) void k_mlp_dw(const float* __restrict__ z4,
                                                const float* __restrict__ dwwq,
                                                const float* __restrict__ dwbq,
                                                float* __restrict__ z4b) {
  int tid = blockIdx.x * 256 + threadIdx.x;
  int hw = tid % HWc;
  int bj = tid / HWc;
  int j = bj % 4;
  int h = hw / Wc, w = hw % Wc;
  const float* zb = z4 + (size_t)bj * HWc;
  float s = 0.f;
#pragma unroll
  for (int ky = 0; ky < 3; ++ky) {
    int y = h + ky - 1;
    if ((unsigned)y >= (unsigned)Hc) continue;
#pragma unroll
    for (int kx = 0; kx < 3; ++kx) {
      int x = w + kx - 1;
      if ((unsigned)x >= (unsigned)Wc) continue;
      s += zb[y * Wc + x] * dwwq[j * 9 + ky * 3 + kx];
    }
  }
  z4b[tid] = gelu_exact(s + dwbq[j]);
}

// ---------------- MLP: f2 (4->96) + ls2 + residual add into out ----------------
__global__ __launch_bounds__(256) void k_mlp2(const float* __restrict__ z4b,
                                              const float* __restrict__ f2wq,
                                              const float* __restrict__ f2bq,
                                              const float* __restrict__ ls2q,
                                              float* __restrict__ out) {
  int pos = blockIdx.x * 256 + threadIdx.x;
  int bb = pos / HWc, hw = pos % HWc;
  const float* zb = z4b + (size_t)bb * 4 * HWc + hw;
  float z0 = zb[0 * HWc], z1 = zb[1 * HWc], z2 = zb[2 * HWc], z3 = zb[3 * HWc];
  float* ob = out + (size_t)bb * Cc * HWc + hw;
  for (int o = 0; o < Cc; ++o) {
    float s = f2bq[o] + z0 * f2wq[o * 4 + 0] + z1 * f2wq[o * 4 + 1]
                      + z2 * f2wq[o * 4 + 2] + z3 * f2wq[o * 4 + 3];
    ob[o * HWc] += ls2q[o] * s;
  }
}

}  // namespace

extern "C" void kernel_launch(void* const* d_in, const int* in_sizes, int n_in,
                              void* d_out, int out_size, void* d_ws, size_t ws_size,
                              hipStream_t stream) {
  (void)in_sizes; (void)n_in; (void)out_size; (void)ws_size;
  const float* x   = (const float*)d_in[0];
  const float* g1n = (const float*)d_in[1];
  const float* b1n = (const float*)d_in[2];
  const float* p1w = (const float*)d_in[3];
  const float* p1b = (const float*)d_in[4];
  const float* o0w = (const float*)d_in[5];
  const float* o0b = (const float*)d_in[6];
  const float* d0w = (const float*)d_in[7];
  const float* d0b = (const float*)d_in[8];
  const float* o1w = (const float*)d_in[9];
  const float* o1b = (const float*)d_in[10];
  const float* d1w = (const float*)d_in[11];
  const float* d1b = (const float*)d_in[12];
  const float* c1w = (const float*)d_in[13];
  const float* c1b = (const float*)d_in[14];
  const float* p2w = (const float*)d_in[15];
  const float* p2b = (const float*)d_in[16];
  const float* ls1 = (const float*)d_in[17];
  const float* g2n = (const float*)d_in[18];
  const float* b2n = (const float*)d_in[19];
  const float* f1w = (const float*)d_in[20];
  const float* f1b = (const float*)d_in[21];
  const float* dww = (const float*)d_in[22];
  const float* dwb = (const float*)d_in[23];
  const float* f2w = (const float*)d_in[24];
  const float* f2b = (const float*)d_in[25];
  const float* ls2 = (const float*)d_in[26];
  float* out = (float*)d_out;
  float* ws  = (float*)d_ws;

  const size_t NC = (size_t)Nc * Cc;
  float* yln   = ws;                                  size_t o_ = NC;
  float* u     = ws + o_;                             o_ += NC;
  float* A     = ws + o_;                             o_ += NC;
  float* y2    = ws + o_;                             o_ += NC;
  float* a1    = ws + o_;                             o_ += NC;
  float* off0t = ws + o_;                             o_ += (size_t)Nc * 64;
  float* off1t = ws + o_;                             o_ += (size_t)Nc * 112;
  float* z4    = ws + o_;                             o_ += (size_t)Bc * 4 * HWc;
  float* z4b   = ws + o_;                             o_ += (size_t)Bc * 4 * HWc;
  float* dwt0  = ws + o_;                             o_ += 25 * Cc;
  float* dwt1  = ws + o_;                             o_ += 49 * Cc;
  unsigned short* u_pad  = (unsigned short*)(ws + o_); o_ += (size_t)Bc * 60 * 60 * Cc / 2;
  unsigned short* a0_pad = (unsigned short*)(ws + o_); o_ += (size_t)Bc * 74 * 74 * Cc / 2;
  unsigned short* wpk0   = (unsigned short*)(ws + o_); o_ += (size_t)25 * 3 * 4 * 512 / 2;
  unsigned short* wpk1   = (unsigned short*)(ws + o_); o_ += (size_t)49 * 3 * 7 * 512 / 2;

  dim3 b256(256, 1, 1), b64x4(64, 4, 1);

  hipMemsetAsync(u_pad, 0, (size_t)Bc * 60 * 60 * Cc * sizeof(unsigned short), stream);
  hipMemsetAsync(a0_pad, 0, (size_t)Bc * 74 * 74 * Cc * sizeof(unsigned short), stream);
  hipLaunchKernelGGL((k_pack_w<5, 4, 50>), dim3((25 * 3 * 4 * 512 + 255) / 256), b256, 0, stream, o0w, wpk0);
  hipLaunchKernelGGL((k_pack_w<7, 7, 98>), dim3((49 * 3 * 7 * 512 + 255) / 256), b256, 0, stream, o1w, wpk1);
  hipLaunchKernelGGL(k_pack_dwt, dim3((25 * Cc + 255) / 256), b256, 0, stream, d0w, dwt0, 25);
  hipLaunchKernelGGL(k_pack_dwt, dim3((49 * Cc + 255) / 256), b256, 0, stream, d1w, dwt1, 49);

  hipLaunchKernelGGL(k_ln, dim3(Nc / 256), b256, 0, stream, x, g1n, b1n, yln);
  hipLaunchKernelGGL((k_pw96<2, 60>), dim3(Nc / 64), b64x4, 0, stream, yln, p1w, p1b, u, u_pad, 1);
  // v3: grid = Nc/16 blocks (in-block m-split). conv5: MT=1; conv7: MT=2.
  hipLaunchKernelGGL((k_conv_mfma<5, 1, 4, 1, 50, 2, 60, 64>), dim3(Nc / 16), b256, 0, stream,
                     u_pad, wpk0, o0b, off0t);
  hipLaunchKernelGGL((k_deform<5, 1, 2, 2, 60, 9, 74, 64>), dim3(Nc * 24 / 256), b256, 0, stream,
                     u_pad, off0t, dwt0, d0b, (float*)nullptr, a0_pad);
  hipLaunchKernelGGL((k_conv_mfma<7, 3, 7, 2, 98, 9, 74, 112>), dim3(Nc / 16), b256, 0, stream,
                     a0_pad, wpk1, o1b, off1t);
  hipLaunchKernelGGL((k_deform<7, 3, 9, 9, 74, 9, 74, 112>), dim3(Nc * 24 / 256), b256, 0, stream,
                     a0_pad, off1t, dwt1, d1b, a1, (unsigned short*)nullptr);
  hipLaunchKernelGGL((k_pw96<2, 60>), dim3(Nc / 64), b64x4, 0, stream, a1, c1w, c1b, A,
                     (unsigned short*)nullptr, 0);
  hipLaunchKernelGGL(k_combine, dim3(Nc / 64), b64x4, 0, stream,
                     x, u, A, yln, p2w, p2b, ls1, y2, out);
  hipLaunchKernelGGL(k_mlp1, dim3(Nc / 256), b256, 0, stream, y2, g2n, b2n, f1w, f1b, z4);
  hipLaunchKernelGGL(k_mlp_dw, dim3(Nc * 4 / 256), b256, 0, stream, z4, dww, dwb, z4b);
  hipLaunchKernelGGL(k_mlp2, dim3(Nc / 256), b256, 0, stream, z4b, f2w, f2b, ls2, out);
}

// Round 6
// 321.429 us; speedup vs baseline: 19.9343x; 1.0556x over previous
//
#include <hip/hip_runtime.h>
#include <math.h>

namespace {

constexpr int Bc = 4, Cc = 96, Hc = 56, Wc = 56;
constexpr int HWc = Hc * Wc;       // 3136
constexpr int Nc  = Bc * HWc;      // 12544
constexpr float EPSc = 1e-5f;

typedef __attribute__((ext_vector_type(8))) short bf16x8;
typedef __attribute__((ext_vector_type(4))) float f32x4;

__device__ __forceinline__ unsigned short f2bf(float f) {
  union { float f; unsigned u; } x; x.f = f;
  unsigned r = x.u + 0x7fffu + ((x.u >> 16) & 1u);
  return (unsigned short)(r >> 16);
}
__device__ __forceinline__ float bf2f(unsigned short u) {
  union { unsigned u; float f; } x; x.u = (unsigned)u << 16; return x.f;
}
__device__ __forceinline__ float gelu_exact(float x) {
  return 0.5f * x * (1.0f + erff(x * 0.7071067811865475f));
}

// ---------------- LayerNorm over channel dim (NCHW) ----------------
__global__ __launch_bounds__(256) void k_ln(const float* __restrict__ x,
                                            const float* __restrict__ g,
                                            const float* __restrict__ b,
                                            float* __restrict__ out) {
  int pos = blockIdx.x * 256 + threadIdx.x;
  int bb = pos / HWc, hw = pos % HWc;
  const float* xb = x + (size_t)bb * Cc * HWc + hw;
  float s = 0.f, s2 = 0.f;
  for (int c = 0; c < Cc; ++c) { float v = xb[c * HWc]; s += v; s2 += v * v; }
  float mu  = s * (1.f / Cc);
  float var = fmaxf(s2 * (1.f / Cc) - mu * mu, 0.f);
  float rs  = rsqrtf(var + EPSc);
  float* ob = out + (size_t)bb * Cc * HWc + hw;
  for (int c = 0; c < Cc; ++c) {
    float v = xb[c * HWc];
    ob[c * HWc] = (v - mu) * rs * g[c] + b[c];
  }
}

// ---------------- 1x1 conv 96->96; optional GELU; optional padded-NHWC-bf16 out ----------------
template <int PADP, int WP>
__global__ __launch_bounds__(256) void k_pw96(const float* __restrict__ src,
                                              const float* __restrict__ wq,
                                              const float* __restrict__ bq,
                                              float* __restrict__ dst,
                                              unsigned short* __restrict__ padOut,
                                              int do_gelu) {
  int spos = blockIdx.x * 64 + threadIdx.x;
  int og = threadIdx.y;                          // wave-uniform
  int bb = spos / HWc, hw = spos % HWc;
  const float* sb = src + (size_t)bb * Cc * HWc + hw;
  float acc[24];
#pragma unroll
  for (int o = 0; o < 24; ++o) acc[o] = 0.f;
  for (int c = 0; c < Cc; ++c) {
    float v = sb[c * HWc];
    const float* wr = wq + (og * 24) * Cc + c;
#pragma unroll
    for (int o = 0; o < 24; ++o) acc[o] += v * wr[o * Cc];
  }
  float* db_ = dst + (size_t)bb * Cc * HWc + hw;
  float res[24];
#pragma unroll
  for (int o = 0; o < 24; ++o) {
    int oc = og * 24 + o;
    float r = acc[o] + bq[oc];
    if (do_gelu) r = gelu_exact(r);
    res[o] = r;
    db_[oc * HWc] = r;
  }
  if (padOut) {
    int h = hw / Wc, w = hw % Wc;
    unsigned short tmp[24];
#pragma unroll
    for (int o = 0; o < 24; ++o) tmp[o] = f2bf(res[o]);
    unsigned short* tb = padOut + (((size_t)bb * (Hc + 2 * PADP) + h + PADP) * WP + w + PADP) * Cc + og * 24;
#pragma unroll
    for (int q = 0; q < 3; ++q)
      *reinterpret_cast<bf16x8*>(tb + q * 8) = *reinterpret_cast<const bf16x8*>(tmp + q * 8);
  }
}

// ---------------- weight pack: W[o][c][ky][kx] -> frag layout bf16 ----------------
template <int K_, int MTILES, int P>
__global__ __launch_bounds__(256) void k_pack_w(const float* __restrict__ wsrc,
                                                unsigned short* __restrict__ wpk) {
  constexpr int TOTAL = K_ * K_ * 3 * MTILES * 512;
  int idx = blockIdx.x * 256 + threadIdx.x;
  if (idx >= TOTAL) return;
  int j    = idx & 7;
  int lane = (idx >> 3) & 63;
  int t    = idx >> 9;             // (p*3+cc)*MTILES + mt
  int mt   = t % MTILES;
  int step = t / MTILES;
  int o = mt * 16 + (lane & 15);
  int k = step * 32 + ((lane >> 4) & 3) * 8 + j;
  int p = k / Cc, c = k % Cc;
  float v = 0.f;
  if (o < P) v = wsrc[(((size_t)o * Cc + c) * K_ + p / K_) * K_ + (p % K_)];
  wpk[idx] = f2bf(v);
}

// ---------------- depthwise weight transpose [C][KK] -> [KK][C] ----------------
__global__ __launch_bounds__(256) void k_pack_dwt(const float* __restrict__ dwsrc,
                                                  float* __restrict__ dwt, int KK) {
  int idx = blockIdx.x * 256 + threadIdx.x;
  if (idx >= KK * Cc) return;
  int p = idx / Cc, c = idx % Cc;
  dwt[idx] = dwsrc[c * KK + p];
}

// ---------------- implicit-GEMM MFMA conv v4 ----------------
// block 256 = 4 waves on ONE 32-position n-tile (NT=2); wave = m-chunk (L1 B-share).
// Register double-buffer (A+B) across taps. Grid: Nc/32 blocks, XCD-swizzled.
template <int K_, int DIL_, int MTILES, int MT, int P, int PADP, int WP, int PSTR>
__global__ __launch_bounds__(256) void k_conv_mfma(const unsigned short* __restrict__ inp,
                                                   const unsigned short* __restrict__ wpk,
                                                   const float* __restrict__ bq,
                                                   float* __restrict__ dstT) {
  constexpr int KK = K_ * K_;
  constexpr int HP = Hc + 2 * PADP;
  constexpr int NBLK = Nc / 32;                  // 392
  int lane = threadIdx.x & 63;
  int wv = threadIdx.x >> 6;
  int bid = blockIdx.x;
  int ntile = (bid & 7) * (NBLK / 8) + (bid >> 3);   // XCD swizzle (392 % 8 == 0)
  int n0 = ntile * 32 + (lane & 15);
  int n1 = n0 + 16;
  int b0 = n0 / HWc, hw0 = n0 % HWc, h0 = hw0 / Wc, w0 = hw0 % Wc;
  int b1 = n1 / HWc, hw1 = n1 % HWc, h1 = hw1 / Wc, w1 = hw1 % Wc;
  int co = ((lane >> 4) & 3) * 8;
  const unsigned short* ib0 = inp + ((size_t)b0 * HP * WP + (size_t)h0 * WP + w0) * Cc + co;
  const unsigned short* ib1 = inp + ((size_t)b1 * HP * WP + (size_t)h1 * WP + w1) * Cc + co;
  const unsigned short* wl = wpk + (size_t)lane * 8;
  int mt0 = wv * MT;
  int mtc[MT];
#pragma unroll
  for (int i = 0; i < MT; ++i) mtc[i] = min(mt0 + i, MTILES - 1);

  f32x4 acc[MT][2];
#pragma unroll
  for (int i = 0; i < MT; ++i) {
    acc[i][0] = (f32x4){0.f, 0.f, 0.f, 0.f};
    acc[i][1] = (f32x4){0.f, 0.f, 0.f, 0.f};
  }

  bf16x8 Bb[3][2], Aa[MT][3];
  // prologue: load tap 0 (offset 0)
#pragma unroll
  for (int cc = 0; cc < 3; ++cc) {
    Bb[cc][0] = *reinterpret_cast<const bf16x8*>(ib0 + cc * 32);
    Bb[cc][1] = *reinterpret_cast<const bf16x8*>(ib1 + cc * 32);
#pragma unroll
    for (int i = 0; i < MT; ++i)
      Aa[i][cc] = *reinterpret_cast<const bf16x8*>(wl + ((size_t)cc * MTILES + mtc[i]) * 512);
  }

#pragma unroll 2
  for (int p = 0; p < KK; ++p) {
    int pn = (p + 1 < KK) ? p + 1 : p;
    size_t toff = (size_t)((pn / K_) * DIL_ * WP + (pn % K_) * DIL_) * Cc;
    const unsigned short* sp0 = ib0 + toff;
    const unsigned short* sp1 = ib1 + toff;
    bf16x8 Bn[3][2], An[MT][3];
#pragma unroll
    for (int cc = 0; cc < 3; ++cc) {
      Bn[cc][0] = *reinterpret_cast<const bf16x8*>(sp0 + cc * 32);
      Bn[cc][1] = *reinterpret_cast<const bf16x8*>(sp1 + cc * 32);
#pragma unroll
      for (int i = 0; i < MT; ++i)
        An[i][cc] = *reinterpret_cast<const bf16x8*>(wl + ((size_t)(pn * 3 + cc) * MTILES + mtc[i]) * 512);
    }
#pragma unroll
    for (int cc = 0; cc < 3; ++cc)
#pragma unroll
      for (int i = 0; i < MT; ++i) {
        acc[i][0] = __builtin_amdgcn_mfma_f32_16x16x32_bf16(Aa[i][cc], Bb[cc][0], acc[i][0], 0, 0, 0);
        acc[i][1] = __builtin_amdgcn_mfma_f32_16x16x32_bf16(Aa[i][cc], Bb[cc][1], acc[i][1], 0, 0, 0);
      }
#pragma unroll
    for (int cc = 0; cc < 3; ++cc) {
      Bb[cc][0] = Bn[cc][0];
      Bb[cc][1] = Bn[cc][1];
#pragma unroll
      for (int i = 0; i < MT; ++i) Aa[i][cc] = An[i][cc];
    }
  }

  int orow = ((lane >> 4) & 3) * 4;
#pragma unroll
  for (int i = 0; i < MT; ++i) {
    int mt = mt0 + i;
    if (mt >= MTILES) break;
#pragma unroll
    for (int nt = 0; nt < 2; ++nt) {
      float4 st;
#pragma unroll
      for (int j = 0; j < 4; ++j) {
        int o = mt * 16 + orow + j;
        float bias = (o < P) ? bq[o] : 0.f;
        ((float*)&st)[j] = acc[i][nt][j] + bias;
      }
      int n = nt ? n1 : n0;
      *reinterpret_cast<float4*>(dstT + (size_t)n * PSTR + mt * 16 + orow) = st;
    }
  }
}

// ---------------- deformable depthwise sampling (bf16 padded NHWC src) ----------------
// offT: [pos][PSTR] transposed offsets; dwt: [KK][C]
template <int K_, int DIL_, int PAD_, int IPADP, int IWP, int OPADP, int OWP, int PSTR>
__global__ __launch_bounds__(256) void k_deform(const unsigned short* __restrict__ srcT,
                                                const float* __restrict__ offT,
                                                const float* __restrict__ dwt,
                                                const float* __restrict__ dbq,
                                                float* __restrict__ dst,
                                                unsigned short* __restrict__ dstPad) {
  constexpr int KK = K_ * K_;
  constexpr int KK4 = KK & ~3;
  constexpr int IHP = Hc + 2 * IPADP;
  int tid = blockIdx.x * 256 + threadIdx.x;      // N*24 threads
  int cg = tid % 24;
  int pos = tid / 24;
  int c = cg * 4;
  int bb = pos / HWc, hw = pos % HWc;
  int h = hw / Wc, w = hw % Wc;
  const unsigned short* sb = srcT + (size_t)bb * IHP * IWP * Cc + c;
  const float* ob = offT + (size_t)pos * PSTR;
  float ax = 0.f, ay = 0.f, az = 0.f, aw = 0.f;

  for (int pg = 0; pg < KK4; pg += 4) {
    float4 o01 = *reinterpret_cast<const float4*>(ob + 2 * pg);
    float4 o23 = *reinterpret_cast<const float4*>(ob + 2 * pg + 4);
    float oyv[4] = {o01.x, o01.z, o23.x, o23.z};
    float oxv[4] = {o01.y, o01.w, o23.y, o23.w};
    uint2 v[4][4];
    float wt[4][4];
#pragma unroll
    for (int i = 0; i < 4; ++i) {
      int p = pg + i;
      float py = (float)(h + (p / K_) * DIL_ - PAD_) + oyv[i];
      float px = (float)(w + (p % K_) * DIL_ - PAD_) + oxv[i];
      float y0f = floorf(py), x0f = floorf(px);
      float wy = py - y0f, wx = px - x0f;
      int y0 = (int)y0f, x0 = (int)x0f;
#pragma unroll
      for (int dy = 0; dy < 2; ++dy) {
        int yi = y0 + dy;
        bool yv = (unsigned)yi < (unsigned)Hc;
        int yc = min(max(yi, 0), Hc - 1);
        float wyv = dy ? wy : 1.f - wy;
#pragma unroll
        for (int dx = 0; dx < 2; ++dx) {
          int xi = x0 + dx;
          bool xv = (unsigned)xi < (unsigned)Wc;
          int xc = min(max(xi, 0), Wc - 1);
          wt[i][dy * 2 + dx] = (yv && xv) ? wyv * (dx ? wx : 1.f - wx) : 0.f;
          v[i][dy * 2 + dx] = *reinterpret_cast<const uint2*>(
              sb + ((size_t)(yc + IPADP) * IWP + (xc + IPADP)) * Cc);
        }
      }
    }
#pragma unroll
    for (int i = 0; i < 4; ++i) {
      int p = pg + i;
      float4 d = *reinterpret_cast<const float4*>(dwt + (size_t)p * Cc + c);
      float sx = 0.f, sy = 0.f, sz = 0.f, sw = 0.f;
#pragma unroll
      for (int q = 0; q < 4; ++q) {
        float wq_ = wt[i][q];
        sx += wq_ * bf2f((unsigned short)(v[i][q].x & 0xffffu));
        sy += wq_ * bf2f((unsigned short)(v[i][q].x >> 16));
        sz += wq_ * bf2f((unsigned short)(v[i][q].y & 0xffffu));
        sw += wq_ * bf2f((unsigned short)(v[i][q].y >> 16));
      }
      ax += sx * d.x; ay += sy * d.y; az += sz * d.z; aw += sw * d.w;
    }
  }
  // tail tap (KK % 4 == 1 for K=5,7)
  {
    int p = KK - 1;
    float oy = ob[2 * p], ox = ob[2 * p + 1];
    float py = (float)(h + (p / K_) * DIL_ - PAD_) + oy;
    float px = (float)(w + (p % K_) * DIL_ - PAD_) + ox;
    float y0f = floorf(py), x0f = floorf(px);
    float wy = py - y0f, wx = px - x0f;
    int y0 = (int)y0f, x0 = (int)x0f;
    uint2 v[4]; float wt[4];
#pragma unroll
    for (int dy = 0; dy < 2; ++dy) {
      int yi = y0 + dy;
      bool yv = (unsigned)yi < (unsigned)Hc;
      int yc = min(max(yi, 0), Hc - 1);
      float wyv = dy ? wy : 1.f - wy;
#pragma unroll
      for (int dx = 0; dx < 2; ++dx) {
        int xi = x0 + dx;
        bool xv = (unsigned)xi < (unsigned)Wc;
        int xc = min(max(xi, 0), Wc - 1);
        wt[dy * 2 + dx] = (yv && xv) ? wyv * (dx ? wx : 1.f - wx) : 0.f;
        v[dy * 2 + dx] = *reinterpret_cast<const uint2*>(
            sb + ((size_t)(yc + IPADP) * IWP + (xc + IPADP)) * Cc);
      }
    }
    float4 d = *reinterpret_cast<const float4*>(dwt + (size_t)p * Cc + c);
    float sx = 0.f, sy = 0.f, sz = 0.f, sw = 0.f;
#pragma unroll
    for (int q = 0; q < 4; ++q) {
      sx += wt[q] * bf2f((unsigned short)(v[q].x & 0xffffu));
      sy += wt[q] * bf2f((unsigned short)(v[q].x >> 16));
      sz += wt[q] * bf2f((unsigned short)(v[q].y & 0xffffu));
      sw += wt[q] * bf2f((unsigned short)(v[q].y >> 16));
    }
    ax += sx * d.x; ay += sy * d.y; az += sz * d.z; aw += sw * d.w;
  }

  ax += dbq[c]; ay += dbq[c + 1]; az += dbq[c + 2]; aw += dbq[c + 3];
  if (dst) {
    float* d = dst + (size_t)bb * Cc * HWc + hw;
    d[(c + 0) * HWc] = ax; d[(c + 1) * HWc] = ay;
    d[(c + 2) * HWc] = az; d[(c + 3) * HWc] = aw;
  }
  if (dstPad) {
    unsigned short t4[4] = {f2bf(ax), f2bf(ay), f2bf(az), f2bf(aw)};
    unsigned short* tb = dstPad + (((size_t)bb * (Hc + 2 * OPADP) + h + OPADP) * OWP + w + OPADP) * Cc + c;
    *reinterpret_cast<uint2*>(tb) = *reinterpret_cast<const uint2*>(t4);
  }
}

// ---------------- gated projection + shortcut + ls1 + residual ----------------
__global__ __launch_bounds__(256) void k_combine(const float* __restrict__ x,
                                                 const float* __restrict__ u,
                                                 const float* __restrict__ a,
                                                 const float* __restrict__ yln,
                                                 const float* __restrict__ wq,
                                                 const float* __restrict__ bq,
                                                 const float* __restrict__ ls1q,
                                                 float* __restrict__ y2,
                                                 float* __restrict__ xo) {
  int spos = blockIdx.x * 64 + threadIdx.x;
  int og = threadIdx.y;
  int bb = spos / HWc, hw = spos % HWc;
  size_t base = (size_t)bb * Cc * HWc + hw;
  float acc[24];
#pragma unroll
  for (int o = 0; o < 24; ++o) acc[o] = 0.f;
  for (int c = 0; c < Cc; ++c) {
    float v = u[base + (size_t)c * HWc] * a[base + (size_t)c * HWc];
    const float* wr = wq + (og * 24) * Cc + c;
#pragma unroll
    for (int o = 0; o < 24; ++o) acc[o] += v * wr[o * Cc];
  }
#pragma unroll
  for (int o = 0; o < 24; ++o) {
    int oc = og * 24 + o;
    float t = acc[o] + bq[oc] + yln[base + (size_t)oc * HWc];
    float yv = ls1q[oc] * t;
    y2[base + (size_t)oc * HWc] = yv;
    xo[base + (size_t)oc * HWc] = x[base + (size_t)oc * HWc] + yv;
  }
}

// ---------------- MLP: LN2 + f1 (96->4) ----------------
__global__ __launch_bounds__(256) void k_mlp1(const float* __restrict__ y2,
                                              const float* __restrict__ g,
                                              const float* __restrict__ b,
                                              const float* __restrict__ f1wq,
                                              const float* __restrict__ f1bq,
                                              float* __restrict__ z4) {
  int pos = blockIdx.x * 256 + threadIdx.x;
  int bb = pos / HWc, hw = pos % HWc;
  const float* yb = y2 + (size_t)bb * Cc * HWc + hw;
  float s = 0.f, s2 = 0.f;
  for (int c = 0; c < Cc; ++c) { float v = yb[c * HWc]; s += v; s2 += v * v; }
  float mu  = s * (1.f / Cc);
  float var = fmaxf(s2 * (1.f / Cc) - mu * mu, 0.f);
  float rs  = rsqrtf(var + EPSc);
  float a0 = 0.f, a1 = 0.f, a2 = 0.f, a3 = 0.f;
  for (int c = 0; c < Cc; ++c) {
    float t = (yb[c * HWc] - mu) * rs * g[c] + b[c];
    a0 += t * f1wq[0 * Cc + c];
    a1 += t * f1wq[1 * Cc + c];
    a2 += t * f1wq[2 * Cc + c];
    a3 += t * f1wq[3 * Cc + c];
  }
  float* zb = z4 + (size_t)bb * 4 * HWc + hw;
  zb[0 * HWc] = a0 + f1bq[0];
  zb[1 * HWc] = a1 + f1bq[1];
  zb[2 * HWc] = a2 + f1bq[2];
  zb[3 * HWc] = a3 + f1bq[3];
}

// ---------------- MLP: depthwise 3x3 (4 ch) + GELU ----------------
__global__ __launch_bounds__(256) void k_mlp_dw(const float* __restrict__ z4,
                                                const float* __restrict__ dwwq,
                                                const float* __restrict__ dwbq,
                                                float* __restrict__ z4b) {
  int tid = blockIdx.x * 256 + threadIdx.x;
  int hw = tid % HWc;
  int bj = tid / HWc;
  int j = bj % 4;
  int h = hw / Wc, w = hw % Wc;
  const float* zb = z4 + (size_t)bj * HWc;
  float s = 0.f;
#pragma unroll
  for (int ky = 0; ky < 3; ++ky) {
    int y = h + ky - 1;
    if ((unsigned)y >= (unsigned)Hc) continue;
#pragma unroll
    for (int kx = 0; kx < 3; ++kx) {
      int x = w + kx - 1;
      if ((unsigned)x >= (unsigned)Wc) continue;
      s += zb[y * Wc + x] * dwwq[j * 9 + ky * 3 + kx];
    }
  }
  z4b[tid] = gelu_exact(s + dwbq[j]);
}

// ---------------- MLP: f2 (4->96) + ls2 + residual add into out ----------------
__global__ __launch_bounds__(256) void k_mlp2(const float* __restrict__ z4b,
                                              const float* __restrict__ f2wq,
                                              const float* __restrict__ f2bq,
                                              const float* __restrict__ ls2q,
                                              float* __restrict__ out) {
  int pos = blockIdx.x * 256 + threadIdx.x;
  int bb = pos / HWc, hw = pos % HWc;
  const float* zb = z4b + (size_t)bb * 4 * HWc + hw;
  float z0 = zb[0 * HWc], z1 = zb[1 * HWc], z2 = zb[2 * HWc], z3 = zb[3 * HWc];
  float* ob = out + (size_t)bb * Cc * HWc + hw;
  for (int o = 0; o < Cc; ++o) {
    float s = f2bq[o] + z0 * f2wq[o * 4 + 0] + z1 * f2wq[o * 4 + 1]
                      + z2 * f2wq[o * 4 + 2] + z3 * f2wq[o * 4 + 3];
    ob[o * HWc] += ls2q[o] * s;
  }
}

}  // namespace

extern "C" void kernel_launch(void* const* d_in, const int* in_sizes, int n_in,
                              void* d_out, int out_size, void* d_ws, size_t ws_size,
                              hipStream_t stream) {
  (void)in_sizes; (void)n_in; (void)out_size; (void)ws_size;
  const float* x   = (const float*)d_in[0];
  const float* g1n = (const float*)d_in[1];
  const float* b1n = (const float*)d_in[2];
  const float* p1w = (const float*)d_in[3];
  const float* p1b = (const float*)d_in[4];
  const float* o0w = (const float*)d_in[5];
  const float* o0b = (const float*)d_in[6];
  const float* d0w = (const float*)d_in[7];
  const float* d0b = (const float*)d_in[8];
  const float* o1w = (const float*)d_in[9];
  const float* o1b = (const float*)d_in[10];
  const float* d1w = (const float*)d_in[11];
  const float* d1b = (const float*)d_in[12];
  const float* c1w = (const float*)d_in[13];
  const float* c1b = (const float*)d_in[14];
  const float* p2w = (const float*)d_in[15];
  const float* p2b = (const float*)d_in[16];
  const float* ls1 = (const float*)d_in[17];
  const float* g2n = (const float*)d_in[18];
  const float* b2n = (const float*)d_in[19];
  const float* f1w = (const float*)d_in[20];
  const float* f1b = (const float*)d_in[21];
  const float* dww = (const float*)d_in[22];
  const float* dwb = (const float*)d_in[23];
  const float* f2w = (const float*)d_in[24];
  const float* f2b = (const float*)d_in[25];
  const float* ls2 = (const float*)d_in[26];
  float* out = (float*)d_out;
  float* ws  = (float*)d_ws;

  const size_t NC = (size_t)Nc * Cc;
  float* yln   = ws;                                  size_t o_ = NC;
  float* u     = ws + o_;                             o_ += NC;
  float* A     = ws + o_;                             o_ += NC;
  float* y2    = ws + o_;                             o_ += NC;
  float* a1    = ws + o_;                             o_ += NC;
  float* off0t = ws + o_;                             o_ += (size_t)Nc * 64;
  float* off1t = ws + o_;                             o_ += (size_t)Nc * 112;
  float* z4    = ws + o_;                             o_ += (size_t)Bc * 4 * HWc;
  float* z4b   = ws + o_;                             o_ += (size_t)Bc * 4 * HWc;
  float* dwt0  = ws + o_;                             o_ += 25 * Cc;
  float* dwt1  = ws + o_;                             o_ += 49 * Cc;
  unsigned short* u_pad  = (unsigned short*)(ws + o_); o_ += (size_t)Bc * 60 * 60 * Cc / 2;
  unsigned short* a0_pad = (unsigned short*)(ws + o_); o_ += (size_t)Bc * 74 * 74 * Cc / 2;
  unsigned short* wpk0   = (unsigned short*)(ws + o_); o_ += (size_t)25 * 3 * 4 * 512 / 2;
  unsigned short* wpk1   = (unsigned short*)(ws + o_); o_ += (size_t)49 * 3 * 7 * 512 / 2;

  dim3 b256(256, 1, 1), b64x4(64, 4, 1);

  hipMemsetAsync(u_pad, 0, (size_t)Bc * 60 * 60 * Cc * sizeof(unsigned short), stream);
  hipMemsetAsync(a0_pad, 0, (size_t)Bc * 74 * 74 * Cc * sizeof(unsigned short), stream);
  hipLaunchKernelGGL((k_pack_w<5, 4, 50>), dim3((25 * 3 * 4 * 512 + 255) / 256), b256, 0, stream, o0w, wpk0);
  hipLaunchKernelGGL((k_pack_w<7, 7, 98>), dim3((49 * 3 * 7 * 512 + 255) / 256), b256, 0, stream, o1w, wpk1);
  hipLaunchKernelGGL(k_pack_dwt, dim3((25 * Cc + 255) / 256), b256, 0, stream, d0w, dwt0, 25);
  hipLaunchKernelGGL(k_pack_dwt, dim3((49 * Cc + 255) / 256), b256, 0, stream, d1w, dwt1, 49);

  hipLaunchKernelGGL(k_ln, dim3(Nc / 256), b256, 0, stream, x, g1n, b1n, yln);
  hipLaunchKernelGGL((k_pw96<2, 60>), dim3(Nc / 64), b64x4, 0, stream, yln, p1w, p1b, u, u_pad, 1);
  // v4: grid = Nc/32 blocks (NT=2, in-block m-split). conv5: MT=1; conv7: MT=2.
  hipLaunchKernelGGL((k_conv_mfma<5, 1, 4, 1, 50, 2, 60, 64>), dim3(Nc / 32), b256, 0, stream,
                     u_pad, wpk0, o0b, off0t);
  hipLaunchKernelGGL((k_deform<5, 1, 2, 2, 60, 9, 74, 64>), dim3(Nc * 24 / 256), b256, 0, stream,
                     u_pad, off0t, dwt0, d0b, (float*)nullptr, a0_pad);
  hipLaunchKernelGGL((k_conv_mfma<7, 3, 7, 2, 98, 9, 74, 112>), dim3(Nc / 32), b256, 0, stream,
                     a0_pad, wpk1, o1b, off1t);
  hipLaunchKernelGGL((k_deform<7, 3, 9, 9, 74, 9, 74, 112>), dim3(Nc * 24 / 256), b256, 0, stream,
                     a0_pad, off1t, dwt1, d1b, a1, (unsigned short*)nullptr);
  hipLaunchKernelGGL((k_pw96<2, 60>), dim3(Nc / 64), b64x4, 0, stream, a1, c1w, c1b, A,
                     (unsigned short*)nullptr, 0);
  hipLaunchKernelGGL(k_combine, dim3(Nc / 64), b64x4, 0, stream,
                     x, u, A, yln, p2w, p2b, ls1, y2, out);
  hipLaunchKernelGGL(k_mlp1, dim3(Nc / 256), b256, 0, stream, y2, g2n, b2n, f1w, f1b, z4);
  hipLaunchKernelGGL(k_mlp_dw, dim3(Nc * 4 / 256), b256, 0, stream, z4, dww, dwb, z4b);
  hipLaunchKernelGGL(k_mlp2, dim3(Nc / 256), b256, 0, stream, z4b, f2w, f2b, ls2, out);
}

// Round 7
// 223.676 us; speedup vs baseline: 28.6463x; 1.4370x over previous
//
#include <hip/hip_runtime.h>
#include <math.h>

namespace {

constexpr int Bc = 4, Cc = 96, Hc = 56, Wc = 56;
constexpr int HWc = Hc * Wc;       // 3136
constexpr int Nc  = Bc * HWc;      // 12544
constexpr float EPSc = 1e-5f;

typedef __attribute__((ext_vector_type(8))) short bf16x8;
typedef __attribute__((ext_vector_type(4))) float f32x4;

__device__ __forceinline__ unsigned short f2bf(float f) {
  union { float f; unsigned u; } x; x.f = f;
  unsigned r = x.u + 0x7fffu + ((x.u >> 16) & 1u);
  return (unsigned short)(r >> 16);
}
__device__ __forceinline__ float bf2f(unsigned short u) {
  union { unsigned u; float f; } x; x.u = (unsigned)u << 16; return x.f;
}
__device__ __forceinline__ float gelu_exact(float x) {
  return 0.5f * x * (1.0f + erff(x * 0.7071067811865475f));
}

// ---------------- LayerNorm over channel dim -> bf16 NHWC ----------------
__global__ __launch_bounds__(256) void k_ln(const float* __restrict__ x,
                                            const float* __restrict__ g,
                                            const float* __restrict__ b,
                                            unsigned short* __restrict__ outN) {
  int pos = blockIdx.x * 256 + threadIdx.x;
  int bb = pos / HWc, hw = pos % HWc;
  const float* xb = x + (size_t)bb * Cc * HWc + hw;
  float s = 0.f, s2 = 0.f;
  for (int c = 0; c < Cc; ++c) { float v = xb[c * HWc]; s += v; s2 += v * v; }
  float mu  = s * (1.f / Cc);
  float var = fmaxf(s2 * (1.f / Cc) - mu * mu, 0.f);
  float rs  = rsqrtf(var + EPSc);
  unsigned short* ob = outN + (size_t)pos * Cc;
  for (int q = 0; q < 12; ++q) {
    unsigned short t8[8];
#pragma unroll
    for (int j = 0; j < 8; ++j) {
      int c = q * 8 + j;
      t8[j] = f2bf((xb[c * HWc] - mu) * rs * g[c] + b[c]);
    }
    *reinterpret_cast<bf16x8*>(ob + q * 8) = *reinterpret_cast<const bf16x8*>(t8);
  }
}

// ---------------- weight pack: W[o][c][ky][kx] -> frag layout bf16 ----------------
template <int K_, int MTILES, int P>
__global__ __launch_bounds__(256) void k_pack_w(const float* __restrict__ wsrc,
                                                unsigned short* __restrict__ wpk) {
  constexpr int TOTAL = K_ * K_ * 3 * MTILES * 512;
  int idx = blockIdx.x * 256 + threadIdx.x;
  if (idx >= TOTAL) return;
  int j    = idx & 7;
  int lane = (idx >> 3) & 63;
  int t    = idx >> 9;             // (p*3+cc)*MTILES + mt
  int mt   = t % MTILES;
  int step = t / MTILES;
  int o = mt * 16 + (lane & 15);
  int k = step * 32 + ((lane >> 4) & 3) * 8 + j;
  int p = k / Cc, c = k % Cc;
  float v = 0.f;
  if (o < P) v = wsrc[(((size_t)o * Cc + c) * K_ + p / K_) * K_ + (p % K_)];
  wpk[idx] = f2bf(v);
}

// ---------------- depthwise weight transpose [C][KK] -> [KK][C] ----------------
__global__ __launch_bounds__(256) void k_pack_dwt(const float* __restrict__ dwsrc,
                                                  float* __restrict__ dwt, int KK) {
  int idx = blockIdx.x * 256 + threadIdx.x;
  if (idx >= KK * Cc) return;
  int p = idx / Cc, c = idx % Cc;
  dwt[idx] = dwsrc[c * KK + p];
}

// ---------------- pointwise 96x96 MFMA GEMM: bf16 NHWC in -> bf16 (padded) NHWC out ----------
// block 256 = 4 waves: wave wv -> (ng = wv&1 n-half of 16 pos, mg = wv>>1 m-half of 48 outs).
template <int GELU, int PADP, int WP>
__global__ __launch_bounds__(256) void k_pwg(const unsigned short* __restrict__ inN,
                                             const unsigned short* __restrict__ wpk,
                                             const float* __restrict__ bq,
                                             unsigned short* __restrict__ outPad) {
  int lane = threadIdx.x & 63;
  int wv = threadIdx.x >> 6;
  int ng = wv & 1, mg = wv >> 1;
  int n = blockIdx.x * 32 + ng * 16 + (lane & 15);
  int ko = ((lane >> 4) & 3) * 8;
  const unsigned short* ib = inN + (size_t)n * Cc + ko;
  const unsigned short* wl = wpk + (size_t)lane * 8;
  f32x4 acc[3];
#pragma unroll
  for (int m = 0; m < 3; ++m) acc[m] = (f32x4){0.f, 0.f, 0.f, 0.f};
#pragma unroll
  for (int ks = 0; ks < 3; ++ks) {
    bf16x8 bf = *reinterpret_cast<const bf16x8*>(ib + ks * 32);
#pragma unroll
    for (int m = 0; m < 3; ++m) {
      bf16x8 af = *reinterpret_cast<const bf16x8*>(wl + (size_t)(ks * 6 + mg * 3 + m) * 512);
      acc[m] = __builtin_amdgcn_mfma_f32_16x16x32_bf16(af, bf, acc[m], 0, 0, 0);
    }
  }
  int bb = n / HWc, hw = n % HWc;
  int h = hw / Wc, w = hw % Wc;
  unsigned short* ob = outPad + (((size_t)bb * (Hc + 2 * PADP) + h + PADP) * WP + w + PADP) * Cc;
  int orow = ((lane >> 4) & 3) * 4;
#pragma unroll
  for (int m = 0; m < 3; ++m) {
    int o0 = (mg * 3 + m) * 16 + orow;
    float4 bv = *reinterpret_cast<const float4*>(bq + o0);
    unsigned short t4[4];
#pragma unroll
    for (int j = 0; j < 4; ++j) {
      float r = acc[m][j] + ((const float*)&bv)[j];
      if (GELU) r = gelu_exact(r);
      t4[j] = f2bf(r);
    }
    *reinterpret_cast<uint2*>(ob + o0) = *reinterpret_cast<const uint2*>(t4);
  }
}

// ---------------- combine: GEMM p2w over (u*A) + yln + ls1, residual out, y2 NHWC ----------
template <int UPADP, int UWP>
__global__ __launch_bounds__(256) void k_comb(const unsigned short* __restrict__ uPad,
                                              const unsigned short* __restrict__ An,
                                              const unsigned short* __restrict__ wpk,
                                              const float* __restrict__ bq,
                                              const unsigned short* __restrict__ ylnN,
                                              const float* __restrict__ ls1q,
                                              const float* __restrict__ x,
                                              float* __restrict__ out,
                                              unsigned short* __restrict__ y2N) {
  int lane = threadIdx.x & 63;
  int wv = threadIdx.x >> 6;
  int ng = wv & 1, mg = wv >> 1;
  int n = blockIdx.x * 32 + ng * 16 + (lane & 15);
  int ko = ((lane >> 4) & 3) * 8;
  int bb = n / HWc, hw = n % HWc;
  int h = hw / Wc, w = hw % Wc;
  const unsigned short* ub = uPad + (((size_t)bb * (Hc + 2 * UPADP) + h + UPADP) * UWP + w + UPADP) * Cc + ko;
  const unsigned short* ab = An + (size_t)n * Cc + ko;
  const unsigned short* wl = wpk + (size_t)lane * 8;
  f32x4 acc[3];
#pragma unroll
  for (int m = 0; m < 3; ++m) acc[m] = (f32x4){0.f, 0.f, 0.f, 0.f};
#pragma unroll
  for (int ks = 0; ks < 3; ++ks) {
    bf16x8 uv = *reinterpret_cast<const bf16x8*>(ub + ks * 32);
    bf16x8 av = *reinterpret_cast<const bf16x8*>(ab + ks * 32);
    union { bf16x8 v; unsigned short s[8]; } uu, aa, gg;
    uu.v = uv; aa.v = av;
#pragma unroll
    for (int j = 0; j < 8; ++j) gg.s[j] = f2bf(bf2f(uu.s[j]) * bf2f(aa.s[j]));
#pragma unroll
    for (int m = 0; m < 3; ++m) {
      bf16x8 af = *reinterpret_cast<const bf16x8*>(wl + (size_t)(ks * 6 + mg * 3 + m) * 512);
      acc[m] = __builtin_amdgcn_mfma_f32_16x16x32_bf16(af, gg.v, acc[m], 0, 0, 0);
    }
  }
  int orow = ((lane >> 4) & 3) * 4;
  const float* xb = x + (size_t)bb * Cc * HWc + hw;
  float* ob = out + (size_t)bb * Cc * HWc + hw;
#pragma unroll
  for (int m = 0; m < 3; ++m) {
    int o0 = (mg * 3 + m) * 16 + orow;
    float4 bv = *reinterpret_cast<const float4*>(bq + o0);
    float4 lv = *reinterpret_cast<const float4*>(ls1q + o0);
    uint2 yl = *reinterpret_cast<const uint2*>(ylnN + (size_t)n * Cc + o0);
    unsigned short yl4[4];
    *reinterpret_cast<uint2*>(yl4) = yl;
    unsigned short t4[4];
#pragma unroll
    for (int j = 0; j < 4; ++j) {
      float t = acc[m][j] + ((const float*)&bv)[j] + bf2f(yl4[j]);
      float y2 = ((const float*)&lv)[j] * t;
      t4[j] = f2bf(y2);
      ob[(size_t)(o0 + j) * HWc] = xb[(size_t)(o0 + j) * HWc] + y2;
    }
    *reinterpret_cast<uint2*>(y2N + (size_t)n * Cc + o0) = *reinterpret_cast<const uint2*>(t4);
  }
}

// ---------------- implicit-GEMM MFMA conv v4 (unchanged) ----------------
template <int K_, int DIL_, int MTILES, int MT, int P, int PADP, int WP, int PSTR>
__global__ __launch_bounds__(256) void k_conv_mfma(const unsigned short* __restrict__ inp,
                                                   const unsigned short* __restrict__ wpk,
                                                   const float* __restrict__ bq,
                                                   float* __restrict__ dstT) {
  constexpr int KK = K_ * K_;
  constexpr int HP = Hc + 2 * PADP;
  constexpr int NBLK = Nc / 32;                  // 392
  int lane = threadIdx.x & 63;
  int wv = threadIdx.x >> 6;
  int bid = blockIdx.x;
  int ntile = (bid & 7) * (NBLK / 8) + (bid >> 3);   // XCD swizzle (392 % 8 == 0)
  int n0 = ntile * 32 + (lane & 15);
  int n1 = n0 + 16;
  int b0 = n0 / HWc, hw0 = n0 % HWc, h0 = hw0 / Wc, w0 = hw0 % Wc;
  int b1 = n1 / HWc, hw1 = n1 % HWc, h1 = hw1 / Wc, w1 = hw1 % Wc;
  int co = ((lane >> 4) & 3) * 8;
  const unsigned short* ib0 = inp + ((size_t)b0 * HP * WP + (size_t)h0 * WP + w0) * Cc + co;
  const unsigned short* ib1 = inp + ((size_t)b1 * HP * WP + (size_t)h1 * WP + w1) * Cc + co;
  const unsigned short* wl = wpk + (size_t)lane * 8;
  int mt0 = wv * MT;
  int mtc[MT];
#pragma unroll
  for (int i = 0; i < MT; ++i) mtc[i] = min(mt0 + i, MTILES - 1);

  f32x4 acc[MT][2];
#pragma unroll
  for (int i = 0; i < MT; ++i) {
    acc[i][0] = (f32x4){0.f, 0.f, 0.f, 0.f};
    acc[i][1] = (f32x4){0.f, 0.f, 0.f, 0.f};
  }

  bf16x8 Bb[3][2], Aa[MT][3];
#pragma unroll
  for (int cc = 0; cc < 3; ++cc) {
    Bb[cc][0] = *reinterpret_cast<const bf16x8*>(ib0 + cc * 32);
    Bb[cc][1] = *reinterpret_cast<const bf16x8*>(ib1 + cc * 32);
#pragma unroll
    for (int i = 0; i < MT; ++i)
      Aa[i][cc] = *reinterpret_cast<const bf16x8*>(wl + ((size_t)cc * MTILES + mtc[i]) * 512);
  }

#pragma unroll 2
  for (int p = 0; p < KK; ++p) {
    int pn = (p + 1 < KK) ? p + 1 : p;
    size_t toff = (size_t)((pn / K_) * DIL_ * WP + (pn % K_) * DIL_) * Cc;
    const unsigned short* sp0 = ib0 + toff;
    const unsigned short* sp1 = ib1 + toff;
    bf16x8 Bn[3][2], An[MT][3];
#pragma unroll
    for (int cc = 0; cc < 3; ++cc) {
      Bn[cc][0] = *reinterpret_cast<const bf16x8*>(sp0 + cc * 32);
      Bn[cc][1] = *reinterpret_cast<const bf16x8*>(sp1 + cc * 32);
#pragma unroll
      for (int i = 0; i < MT; ++i)
        An[i][cc] = *reinterpret_cast<const bf16x8*>(wl + ((size_t)(pn * 3 + cc) * MTILES + mtc[i]) * 512);
    }
#pragma unroll
    for (int cc = 0; cc < 3; ++cc)
#pragma unroll
      for (int i = 0; i < MT; ++i) {
        acc[i][0] = __builtin_amdgcn_mfma_f32_16x16x32_bf16(Aa[i][cc], Bb[cc][0], acc[i][0], 0, 0, 0);
        acc[i][1] = __builtin_amdgcn_mfma_f32_16x16x32_bf16(Aa[i][cc], Bb[cc][1], acc[i][1], 0, 0, 0);
      }
#pragma unroll
    for (int cc = 0; cc < 3; ++cc) {
      Bb[cc][0] = Bn[cc][0];
      Bb[cc][1] = Bn[cc][1];
#pragma unroll
      for (int i = 0; i < MT; ++i) Aa[i][cc] = An[i][cc];
    }
  }

  int orow = ((lane >> 4) & 3) * 4;
#pragma unroll
  for (int i = 0; i < MT; ++i) {
    int mt = mt0 + i;
    if (mt >= MTILES) break;
#pragma unroll
    for (int nt = 0; nt < 2; ++nt) {
      float4 st;
#pragma unroll
      for (int j = 0; j < 4; ++j) {
        int o = mt * 16 + orow + j;
        float bias = (o < P) ? bq[o] : 0.f;
        ((float*)&st)[j] = acc[i][nt][j] + bias;
      }
      int n = nt ? n1 : n0;
      *reinterpret_cast<float4*>(dstT + (size_t)n * PSTR + mt * 16 + orow) = st;
    }
  }
}

// ---------------- deformable depthwise sampling (bf16 padded NHWC src) ----------------
template <int K_, int DIL_, int PAD_, int IPADP, int IWP, int OPADP, int OWP, int PSTR>
__global__ __launch_bounds__(256) void k_deform(const unsigned short* __restrict__ srcT,
                                                const float* __restrict__ offT,
                                                const float* __restrict__ dwt,
                                                const float* __restrict__ dbq,
                                                float* __restrict__ dst,
                                                unsigned short* __restrict__ dstPad) {
  constexpr int KK = K_ * K_;
  constexpr int KK4 = KK & ~3;
  constexpr int IHP = Hc + 2 * IPADP;
  int tid = blockIdx.x * 256 + threadIdx.x;      // N*24 threads
  int cg = tid % 24;
  int pos = tid / 24;
  int c = cg * 4;
  int bb = pos / HWc, hw = pos % HWc;
  int h = hw / Wc, w = hw % Wc;
  const unsigned short* sb = srcT + (size_t)bb * IHP * IWP * Cc + c;
  const float* ob = offT + (size_t)pos * PSTR;
  float ax = 0.f, ay = 0.f, az = 0.f, aw = 0.f;

  for (int pg = 0; pg < KK4; pg += 4) {
    float4 o01 = *reinterpret_cast<const float4*>(ob + 2 * pg);
    float4 o23 = *reinterpret_cast<const float4*>(ob + 2 * pg + 4);
    float oyv[4] = {o01.x, o01.z, o23.x, o23.z};
    float oxv[4] = {o01.y, o01.w, o23.y, o23.w};
    uint2 v[4][4];
    float wt[4][4];
#pragma unroll
    for (int i = 0; i < 4; ++i) {
      int p = pg + i;
      float py = (float)(h + (p / K_) * DIL_ - PAD_) + oyv[i];
      float px = (float)(w + (p % K_) * DIL_ - PAD_) + oxv[i];
      float y0f = floorf(py), x0f = floorf(px);
      float wy = py - y0f, wx = px - x0f;
      int y0 = (int)y0f, x0 = (int)x0f;
#pragma unroll
      for (int dy = 0; dy < 2; ++dy) {
        int yi = y0 + dy;
        bool yv = (unsigned)yi < (unsigned)Hc;
        int yc = min(max(yi, 0), Hc - 1);
        float wyv = dy ? wy : 1.f - wy;
#pragma unroll
        for (int dx = 0; dx < 2; ++dx) {
          int xi = x0 + dx;
          bool xv = (unsigned)xi < (unsigned)Wc;
          int xc = min(max(xi, 0), Wc - 1);
          wt[i][dy * 2 + dx] = (yv && xv) ? wyv * (dx ? wx : 1.f - wx) : 0.f;
          v[i][dy * 2 + dx] = *reinterpret_cast<const uint2*>(
              sb + ((size_t)(yc + IPADP) * IWP + (xc + IPADP)) * Cc);
        }
      }
    }
#pragma unroll
    for (int i = 0; i < 4; ++i) {
      int p = pg + i;
      float4 d = *reinterpret_cast<const float4*>(dwt + (size_t)p * Cc + c);
      float sx = 0.f, sy = 0.f, sz = 0.f, sw = 0.f;
#pragma unroll
      for (int q = 0; q < 4; ++q) {
        float wq_ = wt[i][q];
        sx += wq_ * bf2f((unsigned short)(v[i][q].x & 0xffffu));
        sy += wq_ * bf2f((unsigned short)(v[i][q].x >> 16));
        sz += wq_ * bf2f((unsigned short)(v[i][q].y & 0xffffu));
        sw += wq_ * bf2f((unsigned short)(v[i][q].y >> 16));
      }
      ax += sx * d.x; ay += sy * d.y; az += sz * d.z; aw += sw * d.w;
    }
  }
  // tail tap (KK % 4 == 1 for K=5,7)
  {
    int p = KK - 1;
    float oy = ob[2 * p], ox = ob[2 * p + 1];
    float py = (float)(h + (p / K_) * DIL_ - PAD_) + oy;
    float px = (float)(w + (p % K_) * DIL_ - PAD_) + ox;
    float y0f = floorf(py), x0f = floorf(px);
    float wy = py - y0f, wx = px - x0f;
    int y0 = (int)y0f, x0 = (int)x0f;
    uint2 v[4]; float wt[4];
#pragma unroll
    for (int dy = 0; dy < 2; ++dy) {
      int yi = y0 + dy;
      bool yv = (unsigned)yi < (unsigned)Hc;
      int yc = min(max(yi, 0), Hc - 1);
      float wyv = dy ? wy : 1.f - wy;
#pragma unroll
      for (int dx = 0; dx < 2; ++dx) {
        int xi = x0 + dx;
        bool xv = (unsigned)xi < (unsigned)Wc;
        int xc = min(max(xi, 0), Wc - 1);
        wt[dy * 2 + dx] = (yv && xv) ? wyv * (dx ? wx : 1.f - wx) : 0.f;
        v[dy * 2 + dx] = *reinterpret_cast<const uint2*>(
            sb + ((size_t)(yc + IPADP) * IWP + (xc + IPADP)) * Cc);
      }
    }
    float4 d = *reinterpret_cast<const float4*>(dwt + (size_t)p * Cc + c);
    float sx = 0.f, sy = 0.f, sz = 0.f, sw = 0.f;
#pragma unroll
    for (int q = 0; q < 4; ++q) {
      sx += wt[q] * bf2f((unsigned short)(v[q].x & 0xffffu));
      sy += wt[q] * bf2f((unsigned short)(v[q].x >> 16));
      sz += wt[q] * bf2f((unsigned short)(v[q].y & 0xffffu));
      sw += wt[q] * bf2f((unsigned short)(v[q].y >> 16));
    }
    ax += sx * d.x; ay += sy * d.y; az += sz * d.z; aw += sw * d.w;
  }

  ax += dbq[c]; ay += dbq[c + 1]; az += dbq[c + 2]; aw += dbq[c + 3];
  if (dst) {
    float* d = dst + (size_t)bb * Cc * HWc + hw;
    d[(c + 0) * HWc] = ax; d[(c + 1) * HWc] = ay;
    d[(c + 2) * HWc] = az; d[(c + 3) * HWc] = aw;
  }
  if (dstPad) {
    unsigned short t4[4] = {f2bf(ax), f2bf(ay), f2bf(az), f2bf(aw)};
    unsigned short* tb = dstPad + (((size_t)bb * (Hc + 2 * OPADP) + h + OPADP) * OWP + w + OPADP) * Cc + c;
    *reinterpret_cast<uint2*>(tb) = *reinterpret_cast<const uint2*>(t4);
  }
}

// ---------------- MLP: LN2 + f1 (96->4), y2 in bf16 NHWC ----------------
__global__ __launch_bounds__(256) void k_mlp1(const unsigned short* __restrict__ y2N,
                                              const float* __restrict__ g,
                                              const float* __restrict__ b,
                                              const float* __restrict__ f1wq,
                                              const float* __restrict__ f1bq,
                                              float* __restrict__ z4) {
  int pos = blockIdx.x * 256 + threadIdx.x;
  int bb = pos / HWc, hw = pos % HWc;
  const unsigned short* yb = y2N + (size_t)pos * Cc;
  float vv[96];
  float s = 0.f, s2 = 0.f;
#pragma unroll
  for (int q = 0; q < 12; ++q) {
    bf16x8 t = *reinterpret_cast<const bf16x8*>(yb + q * 8);
    union { bf16x8 v; unsigned short s[8]; } u; u.v = t;
#pragma unroll
    for (int j = 0; j < 8; ++j) {
      float f = bf2f(u.s[j]);
      vv[q * 8 + j] = f; s += f; s2 += f * f;
    }
  }
  float mu  = s * (1.f / Cc);
  float var = fmaxf(s2 * (1.f / Cc) - mu * mu, 0.f);
  float rs  = rsqrtf(var + EPSc);
  float a0 = 0.f, a1 = 0.f, a2 = 0.f, a3 = 0.f;
#pragma unroll
  for (int c = 0; c < 96; ++c) {
    float t = (vv[c] - mu) * rs * g[c] + b[c];
    a0 += t * f1wq[0 * Cc + c];
    a1 += t * f1wq[1 * Cc + c];
    a2 += t * f1wq[2 * Cc + c];
    a3 += t * f1wq[3 * Cc + c];
  }
  float* zb = z4 + (size_t)bb * 4 * HWc + hw;
  zb[0 * HWc] = a0 + f1bq[0];
  zb[1 * HWc] = a1 + f1bq[1];
  zb[2 * HWc] = a2 + f1bq[2];
  zb[3 * HWc] = a3 + f1bq[3];
}

// ---------------- MLP: depthwise 3x3 (4 ch) + GELU ----------------
__global__ __launch_bounds__(256) void k_mlp_dw(const float* __restrict__ z4,
                                                const float* __restrict__ dwwq,
                                                const float* __restrict__ dwbq,
                                                float* __restrict__ z4b) {
  int tid = blockIdx.x * 256 + threadIdx.x;
  int hw = tid % HWc;
  int bj = tid / HWc;
  int j = bj % 4;
  int h = hw / Wc, w = hw % Wc;
  const float* zb = z4 + (size_t)bj * HWc;
  float s = 0.f;
#pragma unroll
  for (int ky = 0; ky < 3; ++ky) {
    int y = h + ky - 1;
    if ((unsigned)y >= (unsigned)Hc) continue;
#pragma unroll
    for (int kx = 0; kx < 3; ++kx) {
      int x = w + kx - 1;
      if ((unsigned)x >= (unsigned)Wc) continue;
      s += zb[y * Wc + x] * dwwq[j * 9 + ky * 3 + kx];
    }
  }
  z4b[tid] = gelu_exact(s + dwbq[j]);
}

// ---------------- MLP: f2 (4->96) + ls2 + residual add into out ----------------
__global__ __launch_bounds__(256) void k_mlp2(const float* __restrict__ z4b,
                                              const float* __restrict__ f2wq,
                                              const float* __restrict__ f2bq,
                                              const float* __restrict__ ls2q,
                                              float* __restrict__ out) {
  int pos = blockIdx.x * 256 + threadIdx.x;
  int bb = pos / HWc, hw = pos % HWc;
  const float* zb = z4b + (size_t)bb * 4 * HWc + hw;
  float z0 = zb[0 * HWc], z1 = zb[1 * HWc], z2 = zb[2 * HWc], z3 = zb[3 * HWc];
  float* ob = out + (size_t)bb * Cc * HWc + hw;
  for (int o = 0; o < Cc; ++o) {
    float s = f2bq[o] + z0 * f2wq[o * 4 + 0] + z1 * f2wq[o * 4 + 1]
                      + z2 * f2wq[o * 4 + 2] + z3 * f2wq[o * 4 + 3];
    ob[o * HWc] += ls2q[o] * s;
  }
}

}  // namespace

extern "C" void kernel_launch(void* const* d_in, const int* in_sizes, int n_in,
                              void* d_out, int out_size, void* d_ws, size_t ws_size,
                              hipStream_t stream) {
  (void)in_sizes; (void)n_in; (void)out_size; (void)ws_size;
  const float* x   = (const float*)d_in[0];
  const float* g1n = (const float*)d_in[1];
  const float* b1n = (const float*)d_in[2];
  const float* p1w = (const float*)d_in[3];
  const float* p1b = (const float*)d_in[4];
  const float* o0w = (const float*)d_in[5];
  const float* o0b = (const float*)d_in[6];
  const float* d0w = (const float*)d_in[7];
  const float* d0b = (const float*)d_in[8];
  const float* o1w = (const float*)d_in[9];
  const float* o1b = (const float*)d_in[10];
  const float* d1w = (const float*)d_in[11];
  const float* d1b = (const float*)d_in[12];
  const float* c1w = (const float*)d_in[13];
  const float* c1b = (const float*)d_in[14];
  const float* p2w = (const float*)d_in[15];
  const float* p2b = (const float*)d_in[16];
  const float* ls1 = (const float*)d_in[17];
  const float* g2n = (const float*)d_in[18];
  const float* b2n = (const float*)d_in[19];
  const float* f1w = (const float*)d_in[20];
  const float* f1b = (const float*)d_in[21];
  const float* dww = (const float*)d_in[22];
  const float* dwb = (const float*)d_in[23];
  const float* f2w = (const float*)d_in[24];
  const float* f2b = (const float*)d_in[25];
  const float* ls2 = (const float*)d_in[26];
  float* out = (float*)d_out;
  float* ws  = (float*)d_ws;

  float* off0t = ws;                                  size_t o_ = (size_t)Nc * 64;
  float* off1t = ws + o_;                             o_ += (size_t)Nc * 112;
  float* z4    = ws + o_;                             o_ += (size_t)Bc * 4 * HWc;
  float* z4b   = ws + o_;                             o_ += (size_t)Bc * 4 * HWc;
  float* dwt0  = ws + o_;                             o_ += 25 * Cc;
  float* dwt1  = ws + o_;                             o_ += 49 * Cc;
  unsigned short* yln_n  = (unsigned short*)(ws + o_); o_ += (size_t)Nc * Cc / 2;
  unsigned short* a1_n   = (unsigned short*)(ws + o_); o_ += (size_t)Nc * Cc / 2;
  unsigned short* A_n    = (unsigned short*)(ws + o_); o_ += (size_t)Nc * Cc / 2;
  unsigned short* y2_n   = (unsigned short*)(ws + o_); o_ += (size_t)Nc * Cc / 2;
  unsigned short* u_pad  = (unsigned short*)(ws + o_); o_ += (size_t)Bc * 60 * 60 * Cc / 2;
  unsigned short* a0_pad = (unsigned short*)(ws + o_); o_ += (size_t)Bc * 74 * 74 * Cc / 2;
  unsigned short* wpk0   = (unsigned short*)(ws + o_); o_ += (size_t)25 * 3 * 4 * 512 / 2;
  unsigned short* wpk1   = (unsigned short*)(ws + o_); o_ += (size_t)49 * 3 * 7 * 512 / 2;
  unsigned short* wpkp1  = (unsigned short*)(ws + o_); o_ += (size_t)3 * 6 * 512 / 2;
  unsigned short* wpkc1  = (unsigned short*)(ws + o_); o_ += (size_t)3 * 6 * 512 / 2;
  unsigned short* wpkp2  = (unsigned short*)(ws + o_); o_ += (size_t)3 * 6 * 512 / 2;

  dim3 b256(256, 1, 1);

  hipMemsetAsync(u_pad, 0, (size_t)Bc * 60 * 60 * Cc * sizeof(unsigned short), stream);
  hipMemsetAsync(a0_pad, 0, (size_t)Bc * 74 * 74 * Cc * sizeof(unsigned short), stream);
  hipLaunchKernelGGL((k_pack_w<5, 4, 50>), dim3((25 * 3 * 4 * 512 + 255) / 256), b256, 0, stream, o0w, wpk0);
  hipLaunchKernelGGL((k_pack_w<7, 7, 98>), dim3((49 * 3 * 7 * 512 + 255) / 256), b256, 0, stream, o1w, wpk1);
  hipLaunchKernelGGL((k_pack_w<1, 6, 96>), dim3((3 * 6 * 512 + 255) / 256), b256, 0, stream, p1w, wpkp1);
  hipLaunchKernelGGL((k_pack_w<1, 6, 96>), dim3((3 * 6 * 512 + 255) / 256), b256, 0, stream, c1w, wpkc1);
  hipLaunchKernelGGL((k_pack_w<1, 6, 96>), dim3((3 * 6 * 512 + 255) / 256), b256, 0, stream, p2w, wpkp2);
  hipLaunchKernelGGL(k_pack_dwt, dim3((25 * Cc + 255) / 256), b256, 0, stream, d0w, dwt0, 25);
  hipLaunchKernelGGL(k_pack_dwt, dim3((49 * Cc + 255) / 256), b256, 0, stream, d1w, dwt1, 49);

  hipLaunchKernelGGL(k_ln, dim3(Nc / 256), b256, 0, stream, x, g1n, b1n, yln_n);
  hipLaunchKernelGGL((k_pwg<1, 2, 60>), dim3(Nc / 32), b256, 0, stream, yln_n, wpkp1, p1b, u_pad);
  hipLaunchKernelGGL((k_conv_mfma<5, 1, 4, 1, 50, 2, 60, 64>), dim3(Nc / 32), b256, 0, stream,
                     u_pad, wpk0, o0b, off0t);
  hipLaunchKernelGGL((k_deform<5, 1, 2, 2, 60, 9, 74, 64>), dim3(Nc * 24 / 256), b256, 0, stream,
                     u_pad, off0t, dwt0, d0b, (float*)nullptr, a0_pad);
  hipLaunchKernelGGL((k_conv_mfma<7, 3, 7, 2, 98, 9, 74, 112>), dim3(Nc / 32), b256, 0, stream,
                     a0_pad, wpk1, o1b, off1t);
  hipLaunchKernelGGL((k_deform<7, 3, 9, 9, 74, 0, 56, 112>), dim3(Nc * 24 / 256), b256, 0, stream,
                     a0_pad, off1t, dwt1, d1b, (float*)nullptr, a1_n);
  hipLaunchKernelGGL((k_pwg<0, 0, 56>), dim3(Nc / 32), b256, 0, stream, a1_n, wpkc1, c1b, A_n);
  hipLaunchKernelGGL((k_comb<2, 60>), dim3(Nc / 32), b256, 0, stream,
                     u_pad, A_n, wpkp2, p2b, yln_n, ls1, x, out, y2_n);
  hipLaunchKernelGGL(k_mlp1, dim3(Nc / 256), b256, 0, stream, y2_n, g2n, b2n, f1w, f1b, z4);
  hipLaunchKernelGGL(k_mlp_dw, dim3(Nc * 4 / 256), b256, 0, stream, z4, dww, dwb, z4b);
  hipLaunchKernelGGL(k_mlp2, dim3(Nc / 256), b256, 0, stream, z4b, f2w, f2b, ls2, out);
}